// Round 5
// baseline (4085.320 us; speedup 1.0000x reference)
//
#include <hip/hip_runtime.h>
#include <hip/hip_bf16.h>
#include <math.h>

// MoE: T=65536 tokens, D=512, H=1024, E=8, TOP_K=2.
// R5: expert uses raw s_barrier + counted vmcnt(2) (loads stay in flight
// across barriers - T3/T4); gate split into gemm1 + gate2 for visibility,
// gemm1 LDS reads conflict-free, gate2 block-aggregated scatter.

typedef __attribute__((ext_vector_type(8))) short bf16x8;
typedef __attribute__((ext_vector_type(4))) float f32x4;

__device__ __forceinline__ unsigned short f2bf(float f){
  unsigned u = __builtin_bit_cast(unsigned, f);
  u += 0x7FFFu + ((u >> 16) & 1u);          // RNE
  return (unsigned short)(u >> 16);
}

__device__ __forceinline__ bf16x8 cvt8(float4 f0, float4 f1){
  bf16x8 r;
  r[0]=(short)f2bf(f0.x); r[1]=(short)f2bf(f0.y); r[2]=(short)f2bf(f0.z); r[3]=(short)f2bf(f0.w);
  r[4]=(short)f2bf(f1.x); r[5]=(short)f2bf(f1.y); r[6]=(short)f2bf(f1.z); r[7]=(short)f2bf(f1.w);
  return r;
}

__device__ __forceinline__ void gload16(const void* g, void* l){
  __builtin_amdgcn_global_load_lds((const __attribute__((address_space(1))) unsigned int*)g,
                                   (__attribute__((address_space(3))) unsigned int*)l, 16, 0, 0);
}

#define VW2() asm volatile("s_waitcnt vmcnt(2)" ::: "memory")
#define BAR() __builtin_amdgcn_s_barrier()
#define SB0() __builtin_amdgcn_sched_barrier(0)

// ---------------------------------------------------------------------------
// x fp32 -> bf16 cache
// ---------------------------------------------------------------------------
__global__ __launch_bounds__(256)
void xcvt_kernel(const float* __restrict__ x, unsigned short* __restrict__ xbf){
  int i = blockIdx.x * 256 + threadIdx.x;
  const float4 f0 = ((const float4*)x)[(size_t)i * 2];
  const float4 f1 = ((const float4*)x)[(size_t)i * 2 + 1];
  ushort4 o0, o1;
  o0.x = f2bf(f0.x); o0.y = f2bf(f0.y); o0.z = f2bf(f0.z); o0.w = f2bf(f0.w);
  o1.x = f2bf(f1.x); o1.y = f2bf(f1.y); o1.z = f2bf(f1.z); o1.w = f2bf(f1.w);
  ((ushort4*)xbf)[(size_t)i * 2]     = o0;
  ((ushort4*)xbf)[(size_t)i * 2 + 1] = o1;
}

// ---------------------------------------------------------------------------
// Transpose + fp32->bf16 convert:  in [E][R][C] f32  ->  out [E][C][R] bf16
// ---------------------------------------------------------------------------
__global__ __launch_bounds__(256, 4)
void transpose_cvt_kernel(const float* __restrict__ in, unsigned short* __restrict__ out,
                          int R, int C){
  const int tilesR = R >> 6, tilesC = C >> 6;
  const int b = blockIdx.x;
  const int e = b / (tilesR * tilesC);
  const int rem = b % (tilesR * tilesC);
  const int rb = (rem / tilesC) << 6;
  const int cb = (rem % tilesC) << 6;
  const float* src = in + (size_t)e * R * C;
  unsigned short* dst = out + (size_t)e * R * C;
  __shared__ float t[64][65];
  const int r0 = threadIdx.x >> 4;
  const int c4 = (threadIdx.x & 15) << 2;
  #pragma unroll
  for (int p = 0; p < 4; ++p){
    int r = r0 + (p << 4);
    const float4 v = *(const float4*)(src + (size_t)(rb + r) * C + cb + c4);
    t[r][c4+0] = v.x; t[r][c4+1] = v.y; t[r][c4+2] = v.z; t[r][c4+3] = v.w;
  }
  __syncthreads();
  #pragma unroll
  for (int p = 0; p < 4; ++p){
    int cr = r0 + (p << 4);
    ushort4 o;
    o.x = f2bf(t[c4+0][cr]); o.y = f2bf(t[c4+1][cr]);
    o.z = f2bf(t[c4+2][cr]); o.w = f2bf(t[c4+3][cr]);
    *(ushort4*)(dst + (size_t)(cb + cr) * R + rb + c4) = o;
  }
}

// ---------------------------------------------------------------------------
// Gate GEMM1: h = relu(x @ gw1 + gb1), fp32, h[65536][256] to ws.
// 1024 blocks x 256 thr x 64 tokens. Wave w owns tokens [16w,16w+16);
// lane l owns cols [4l,4l+4). LDS reads: wv = full 1KB row per inst
// (conflict-free); xv = same-address broadcast (free).
// ---------------------------------------------------------------------------
__global__ __launch_bounds__(256, 3)
void gate_gemm1_kernel(const float* __restrict__ x, const float* __restrict__ gw1,
                       const float* __restrict__ gb1, float* __restrict__ h){
  __shared__ float xs[2][16][68];       // [buf][k][tok]
  __shared__ float g1s[2][16][256];     // [buf][k][col]
  const int tid = threadIdx.x;
  const int t0 = blockIdx.x << 6;
  const int w = tid >> 6, ln = tid & 63;

  const int xtok = tid >> 2, xk4 = (tid & 3) << 2;
  const int gr = tid >> 6;              // 0..3
  const int gc = (tid & 63) << 2;       // 0..252

  float4 nx;
  float4 ng[4];
  { // prologue: tile 0
    nx = *(const float4*)(x + (size_t)(t0 + xtok) * 512 + xk4);
    #pragma unroll
    for (int p = 0; p < 4; ++p)
      ng[p] = *(const float4*)(gw1 + (size_t)((p << 2) + gr) * 256 + gc);
    xs[0][xk4+0][xtok] = nx.x; xs[0][xk4+1][xtok] = nx.y;
    xs[0][xk4+2][xtok] = nx.z; xs[0][xk4+3][xtok] = nx.w;
    #pragma unroll
    for (int p = 0; p < 4; ++p)
      *(float4*)&g1s[0][(p << 2) + gr][gc] = ng[p];
  }
  __syncthreads();

  float acc[16][4];
  #pragma unroll
  for (int t = 0; t < 16; ++t)
    #pragma unroll
    for (int c = 0; c < 4; ++c) acc[t][c] = 0.f;

  int cur = 0;
  for (int it = 0; it < 32; ++it){
    const int kb = (it + 1) << 4;
    if (it < 31){
      nx = *(const float4*)(x + (size_t)(t0 + xtok) * 512 + kb + xk4);
      #pragma unroll
      for (int p = 0; p < 4; ++p)
        ng[p] = *(const float4*)(gw1 + (size_t)(kb + (p << 2) + gr) * 256 + gc);
    }
    #pragma unroll
    for (int k = 0; k < 16; ++k){
      const float4 wv = *(const float4*)&g1s[cur][k][ln << 2];
      float4 xq[4];
      #pragma unroll
      for (int q = 0; q < 4; ++q)
        xq[q] = *(const float4*)&xs[cur][k][(w << 4) + (q << 2)];
      #pragma unroll
      for (int t = 0; t < 16; ++t){
        const float xv = ((const float*)&xq[t >> 2])[t & 3];
        acc[t][0] = fmaf(xv, wv.x, acc[t][0]);
        acc[t][1] = fmaf(xv, wv.y, acc[t][1]);
        acc[t][2] = fmaf(xv, wv.z, acc[t][2]);
        acc[t][3] = fmaf(xv, wv.w, acc[t][3]);
      }
    }
    if (it < 31){
      xs[cur^1][xk4+0][xtok] = nx.x; xs[cur^1][xk4+1][xtok] = nx.y;
      xs[cur^1][xk4+2][xtok] = nx.z; xs[cur^1][xk4+3][xtok] = nx.w;
      #pragma unroll
      for (int p = 0; p < 4; ++p)
        *(float4*)&g1s[cur^1][(p << 2) + gr][gc] = ng[p];
    }
    __syncthreads();
    cur ^= 1;
  }

  const float4 bias = *(const float4*)(gb1 + (ln << 2));
  #pragma unroll
  for (int t = 0; t < 16; ++t){
    float4 o;
    o.x = fmaxf(acc[t][0] + bias.x, 0.f);
    o.y = fmaxf(acc[t][1] + bias.y, 0.f);
    o.z = fmaxf(acc[t][2] + bias.z, 0.f);
    o.w = fmaxf(acc[t][3] + bias.w, 0.f);
    *(float4*)&h[(size_t)(t0 + (w << 4) + t) * 256 + (ln << 2)] = o;
  }
}

// ---------------------------------------------------------------------------
// Gate2: logits = h @ gw2 + gb2; softmax; top2; re-softmax; block-aggregated
// scatter (LDS lists, 8 global atomics per block).
// 256 blocks x 256 thr, 1 token/thread.
// ---------------------------------------------------------------------------
__global__ __launch_bounds__(256, 2)
void gate2_kernel(const float* __restrict__ h, const float* __restrict__ gw2,
                  const float* __restrict__ gb2,
                  int* __restrict__ counts, int* __restrict__ pair_tok,
                  float* __restrict__ pair_w){
  __shared__ float g2s[256 * 9];
  __shared__ int   lcnt[8];
  __shared__ int   lbase[8];
  __shared__ int   lpre[9];
  __shared__ int   ltok[8][256];
  __shared__ float lw[8][256];
  const int tid = threadIdx.x;
  const int t0 = blockIdx.x << 8;

  #pragma unroll
  for (int p = 0; p < 8; ++p){
    int idx = tid + (p << 8);
    g2s[(idx >> 3) * 9 + (idx & 7)] = gw2[idx];
  }
  if (tid < 8) lcnt[tid] = 0;
  __syncthreads();

  const int token = t0 + tid;
  float pl[8];
  #pragma unroll
  for (int e = 0; e < 8; ++e) pl[e] = gb2[e];
  for (int j = 0; j < 64; ++j){
    const float4 hv = *(const float4*)(h + (size_t)token * 256 + (j << 2));
    #pragma unroll
    for (int i = 0; i < 4; ++i){
      const float hx = ((const float*)&hv)[i];
      #pragma unroll
      for (int e = 0; e < 8; ++e)
        pl[e] = fmaf(hx, g2s[((j << 2) + i) * 9 + e], pl[e]);
    }
  }
  float m = pl[0];
  #pragma unroll
  for (int e = 1; e < 8; ++e) m = fmaxf(m, pl[e]);
  float p[8]; float s = 0.f;
  #pragma unroll
  for (int e = 0; e < 8; ++e){ p[e] = expf(pl[e] - m); s += p[e]; }
  float inv = 1.f / s;
  float m1 = -1.f, m2 = -1.f; int i1 = 0, i2 = 0;
  #pragma unroll
  for (int e = 0; e < 8; ++e){
    float pe = p[e] * inv;
    if (pe > m1){ m2 = m1; i2 = i1; m1 = pe; i1 = e; }
    else if (pe > m2){ m2 = pe; i2 = e; }
  }
  float e21 = expf(m2 - m1);
  float w1 = 1.f / (1.f + e21);
  float w2 = 1.f - w1;
  int p1 = atomicAdd(&lcnt[i1], 1); ltok[i1][p1] = token; lw[i1][p1] = w1;
  int p2 = atomicAdd(&lcnt[i2], 1); ltok[i2][p2] = token; lw[i2][p2] = w2;
  __syncthreads();
  if (tid < 8) lbase[tid] = atomicAdd(&counts[tid], lcnt[tid]);
  if (tid == 0){
    lpre[0] = 0;
    #pragma unroll
    for (int e = 0; e < 8; ++e) lpre[e+1] = lpre[e] + lcnt[e];
  }
  __syncthreads();
  const int total = lpre[8];
  for (int idx = tid; idx < total; idx += 256){
    int e = 0;
    #pragma unroll
    for (int q = 0; q < 7; ++q) e += (idx >= lpre[q + 1]) ? 1 : 0;
    const int i = idx - lpre[e];
    const int dst = (e << 16) + lbase[e] + i;
    pair_tok[dst] = ltok[e][i];
    pair_w[dst]   = lw[e][i];
  }
}

// ---------------------------------------------------------------------------
// Chunk scan
// ---------------------------------------------------------------------------
__global__ void scan_kernel(const int* __restrict__ counts, int* __restrict__ offs){
  if (threadIdx.x == 0){
    int o = 0;
    #pragma unroll
    for (int e = 0; e < 8; ++e){ offs[e] = o; o += (counts[e] + 127) >> 7; }
    offs[8] = o;
  }
}

// ---------------------------------------------------------------------------
// Expert MLP. Compacted grid. 512 thr = 8 waves x 16 token-rows.
// Phase = { issue stage (2 gload16/wave); s_waitcnt vmcnt(2); s_barrier;
//           16 MFMA (setprio); s_barrier }.  Loads stay in flight across
//           barriers (counted vmcnt, never 0 in the loop).
// ---------------------------------------------------------------------------
#define G1_MFMA(S, BUF) do{ \
  __builtin_amdgcn_s_setprio(1); \
  _Pragma("unroll") \
  for (int ct = 0; ct < 4; ++ct){ \
    const int col = (ct << 4) + lrow; \
    const int swc = (col & 7) << 4; \
    _Pragma("unroll") \
    for (int k2 = 0; k2 < 4; ++k2){ \
      const int byt = (col << 8) + ((((k2) << 6) + (kgrp << 4)) ^ swc); \
      bf16x8 bfr = *(const bf16x8*)((const char*)(BUF) + byt); \
      hacc[ct] = __builtin_amdgcn_mfma_f32_16x16x32_bf16(a[(S)*4 + k2], bfr, hacc[ct], 0, 0, 0); \
    } \
  } \
  __builtin_amdgcn_s_setprio(0); \
}while(0)

#define G2_MFMA(NB, BUF) do{ \
  __builtin_amdgcn_s_setprio(1); \
  _Pragma("unroll") \
  for (int nt = 0; nt < 8; ++nt){ \
    const int col = (nt << 4) + lrow; \
    const int swc = (col & 7) << 4; \
    _Pragma("unroll") \
    for (int k2 = 0; k2 < 2; ++k2){ \
      const int byt = (col << 7) + (((k2 << 6) + (kgrp << 4)) ^ swc); \
      bf16x8 bfr = *(const bf16x8*)((const char*)(BUF) + byt); \
      acc[(NB)*8 + nt] = __builtin_amdgcn_mfma_f32_16x16x32_bf16(a2[k2], bfr, acc[(NB)*8 + nt], 0, 0, 0); \
    } \
  } \
  __builtin_amdgcn_s_setprio(0); \
}while(0)

#define PHASE(STAGE_STMT, MFMA_STMT) do{ \
  STAGE_STMT; VW2(); BAR(); SB0(); MFMA_STMT; SB0(); BAR(); }while(0)

__global__ __launch_bounds__(512, 2)
void expert_kernel(const float* __restrict__ x,
                   const unsigned short* __restrict__ xbf,   // may be null
                   const unsigned short* __restrict__ we1T,  // [E][1024][512] bf16
                   const unsigned short* __restrict__ we2T,  // [E][512][1024] bf16
                   const float* __restrict__ be1, const float* __restrict__ be2,
                   const int* __restrict__ counts, const int* __restrict__ offs,
                   const int* __restrict__ pair_tok, const float* __restrict__ pair_w,
                   float* __restrict__ out){
  const int b = blockIdx.x;
  if (b >= offs[8]) return;
  int e = 0;
  #pragma unroll
  for (int q = 0; q < 7; ++q) e += (b >= offs[q + 1]) ? 1 : 0;
  const int cnt = counts[e];
  const int base = (b - offs[e]) << 7;
  const int tid = threadIdx.x;
  const int wv = tid >> 6;
  const int lane = tid & 63;
  const int lrow = lane & 15;
  const int kgrp = lane >> 4;

  __shared__ unsigned short w1s0[64 * 128];
  __shared__ unsigned short w1s1[64 * 128];
  __shared__ unsigned short w2s0[128 * 64];
  __shared__ unsigned short w2s1[128 * 64];
  __shared__ unsigned short hs[128 * 64];

  bf16x8 a[16];
  {
    int r = base + (wv << 4) + lrow;
    int tok = (r < cnt) ? pair_tok[(e << 16) + r] : 0;
    if (xbf){
      const unsigned short* xr = xbf + (size_t)tok * 512 + (kgrp << 3);
      #pragma unroll
      for (int kc = 0; kc < 16; ++kc)
        a[kc] = *(const bf16x8*)(xr + (kc << 5));
    } else {
      const float* xr = x + (size_t)tok * 512 + (kgrp << 3);
      #pragma unroll
      for (int kc = 0; kc < 16; ++kc){
        const float4 f0 = *(const float4*)(xr + (kc << 5));
        const float4 f1 = *(const float4*)(xr + (kc << 5) + 4);
        a[kc] = cvt8(f0, f1);
      }
    }
  }
  f32x4 acc[32];
  #pragma unroll
  for (int i = 0; i < 32; ++i) acc[i] = (f32x4)0.f;

  const unsigned short* w1g = we1T + ((size_t)e << 19);
  const unsigned short* w2g = we2T + ((size_t)e << 19);

  auto stage_w1 = [&](int hcv, int s, unsigned short* buf){
    #pragma unroll
    for (int i = 0; i < 2; ++i){
      int bb = (((wv << 1) + i) << 10) + (lane << 4);
      int row = bb >> 8;
      int inner = bb & 255;
      int srcb = ((hcv + row) << 10) + (s << 8) + (inner ^ ((row & 7) << 4));
      gload16((const char*)w1g + srcb, (char*)buf + (((wv << 1) + i) << 10));
    }
  };
  auto stage_w2 = [&](int hcv, int nb, unsigned short* buf){
    #pragma unroll
    for (int i = 0; i < 2; ++i){
      int bb = (((wv << 1) + i) << 10) + (lane << 4);
      int row = bb >> 7;
      int inner = bb & 127;
      int srcb = (((nb << 7) + row) << 11) + (hcv << 1) + (inner ^ ((row & 7) << 4));
      gload16((const char*)w2g + srcb, (char*)buf + (((wv << 1) + i) << 10));
    }
  };

  stage_w1(0, 0, w1s0);

  for (int hc = 0; hc < 1024; hc += 64){
    f32x4 hacc[4];
    #pragma unroll
    for (int i = 0; i < 4; ++i) hacc[i] = (f32x4)0.f;

    PHASE(stage_w1(hc, 1, w1s1), G1_MFMA(0, w1s0));
    PHASE(stage_w1(hc, 2, w1s0), G1_MFMA(1, w1s1));
    PHASE(stage_w1(hc, 3, w1s1), G1_MFMA(2, w1s0));
    PHASE(stage_w2(hc, 0, w2s0), G1_MFMA(3, w1s1));

    // gelu + store h (wave-local rows; no barrier needed) + read a2
    bf16x8 a2[2];
    {
      char* const hsb = (char*)hs;
      #pragma unroll
      for (int ct = 0; ct < 4; ++ct){
        int colL = (ct << 4) + lrow;
        float bias = be1[(e << 10) + hc + colL];
        #pragma unroll
        for (int rr = 0; rr < 4; ++rr){
          int rowL = (wv << 4) + (kgrp << 2) + rr;
          float v = hacc[ct][rr] + bias;
          float g = 0.5f * v * (1.f + erff(v * 0.70710678118654752f));
          int byt = (rowL << 7) + (colL << 1);
          *(unsigned short*)(hsb + (byt ^ ((rowL & 7) << 4))) = f2bf(g);
        }
      }
      const char* const hsc = (const char*)hs;
      int rowL = (wv << 4) + lrow;
      int swr = (rowL & 7) << 4;
      #pragma unroll
      for (int k2 = 0; k2 < 2; ++k2){
        int byt = (rowL << 7) + (((k2 << 6) + (kgrp << 4)) ^ swr);
        a2[k2] = *(const bf16x8*)(hsc + byt);
      }
    }

    PHASE(stage_w2(hc, 1, w2s1),               G2_MFMA(0, w2s0));
    PHASE(stage_w2(hc, 2, w2s0),               G2_MFMA(1, w2s1));
    PHASE(stage_w2(hc, 3, w2s1),               G2_MFMA(2, w2s0));
    PHASE(stage_w1((hc + 64) & 1023, 0, w1s0), G2_MFMA(3, w2s1));
  }

  // epilogue: weighted atomic accumulate
  #pragma unroll
  for (int rr = 0; rr < 4; ++rr){
    int rowL = (wv << 4) + (kgrp << 2) + rr;
    int rg = base + rowL;
    if (rg < cnt){
      int tok = pair_tok[(e << 16) + rg];
      float wp = pair_w[(e << 16) + rg];
      float* orow = out + (size_t)tok * 512;
      #pragma unroll
      for (int tl = 0; tl < 32; ++tl){
        int col = (tl << 4) + lrow;
        atomicAdd(orow + col, wp * (acc[tl][rr] + be2[(e << 9) + col]));
      }
    }
  }
}

// ---------------------------------------------------------------------------
// Fallback fused gate (R4) - used only if ws too small for h.
// ---------------------------------------------------------------------------
__global__ __launch_bounds__(256, 3)
void gate_fused_kernel(const float* __restrict__ x, const float* __restrict__ gw1,
                       const float* __restrict__ gb1, const float* __restrict__ gw2,
                       const float* __restrict__ gb2,
                       int* __restrict__ counts, int* __restrict__ pair_tok,
                       float* __restrict__ pair_w){
  __shared__ float xs[16][68];
  __shared__ float g1s[16][256];
  __shared__ float g2s[256 * 9];
  __shared__ float b1s[256];
  const int tid = threadIdx.x;
  const int t0 = blockIdx.x << 6;
  const int tg = tid >> 5, cg = tid & 31;
  #pragma unroll
  for (int p = 0; p < 8; ++p){
    int idx = tid + (p << 8);
    g2s[(idx >> 3) * 9 + (idx & 7)] = gw2[idx];
  }
  b1s[tid] = gb1[tid];
  float acc[8][8];
  #pragma unroll
  for (int t = 0; t < 8; ++t)
    #pragma unroll
    for (int j = 0; j < 8; ++j) acc[t][j] = 0.f;
  for (int kb = 0; kb < 512; kb += 16){
    __syncthreads();
    {
      int r = tid >> 2, c = (tid & 3) << 2;
      const float4 v = *(const float4*)(x + (size_t)(t0 + r) * 512 + kb + c);
      xs[c+0][r] = v.x; xs[c+1][r] = v.y; xs[c+2][r] = v.z; xs[c+3][r] = v.w;
    }
    #pragma unroll
    for (int p = 0; p < 4; ++p){
      int f = tid + (p << 8);
      int r = f >> 6, c4 = (f & 63) << 2;
      *(float4*)&g1s[r][c4] = *(const float4*)(gw1 + (size_t)(kb + r) * 256 + c4);
    }
    __syncthreads();
    #pragma unroll
    for (int k = 0; k < 16; ++k){
      float xv[8], wv[8];
      *(float4*)&xv[0] = *(const float4*)&xs[k][tg << 3];
      *(float4*)&xv[4] = *(const float4*)&xs[k][(tg << 3) + 4];
      *(float4*)&wv[0] = *(const float4*)&g1s[k][cg << 2];
      *(float4*)&wv[4] = *(const float4*)&g1s[k][128 + (cg << 2)];
      #pragma unroll
      for (int t = 0; t < 8; ++t)
        #pragma unroll
        for (int j = 0; j < 8; ++j)
          acc[t][j] = fmaf(xv[t], wv[j], acc[t][j]);
    }
  }
  float pl[8][8];
  #pragma unroll
  for (int t = 0; t < 8; ++t)
    #pragma unroll
    for (int e = 0; e < 8; ++e) pl[t][e] = 0.f;
  #pragma unroll
  for (int j = 0; j < 8; ++j){
    int col = (j < 4) ? ((cg << 2) + j) : (128 + (cg << 2) + j - 4);
    float bias = b1s[col];
    #pragma unroll
    for (int t = 0; t < 8; ++t){
      float hv = fmaxf(acc[t][j] + bias, 0.f);
      #pragma unroll
      for (int e = 0; e < 8; ++e)
        pl[t][e] = fmaf(hv, g2s[col * 9 + e], pl[t][e]);
    }
  }
  #pragma unroll
  for (int m = 1; m <= 16; m <<= 1)
    #pragma unroll
    for (int t = 0; t < 8; ++t)
      #pragma unroll
      for (int e = 0; e < 8; ++e)
        pl[t][e] += __shfl_xor(pl[t][e], m, 64);
  if (cg == 0){
    #pragma unroll
    for (int t = 0; t < 8; ++t){
      int token = t0 + (tg << 3) + t;
      float lg[8];
      #pragma unroll
      for (int e = 0; e < 8; ++e) lg[e] = pl[t][e] + gb2[e];
      float m = lg[0];
      #pragma unroll
      for (int e = 1; e < 8; ++e) m = fmaxf(m, lg[e]);
      float p[8]; float s = 0.f;
      #pragma unroll
      for (int e = 0; e < 8; ++e){ p[e] = expf(lg[e] - m); s += p[e]; }
      float inv = 1.f / s;
      float m1 = -1.f, m2 = -1.f; int i1 = 0, i2 = 0;
      #pragma unroll
      for (int e = 0; e < 8; ++e){
        float pe = p[e] * inv;
        if (pe > m1){ m2 = m1; i2 = i1; m1 = pe; i1 = e; }
        else if (pe > m2){ m2 = pe; i2 = e; }
      }
      float e21 = expf(m2 - m1);
      float w1 = 1.f / (1.f + e21);
      float w2 = 1.f - w1;
      int pos1 = atomicAdd(&counts[i1], 1);
      pair_tok[(i1 << 16) + pos1] = token; pair_w[(i1 << 16) + pos1] = w1;
      int pos2 = atomicAdd(&counts[i2], 1);
      pair_tok[(i2 << 16) + pos2] = token; pair_w[(i2 << 16) + pos2] = w2;
    }
  }
}

// ---------------------------------------------------------------------------
extern "C" void kernel_launch(void* const* d_in, const int* in_sizes, int n_in,
                              void* d_out, int out_size, void* d_ws, size_t ws_size,
                              hipStream_t stream){
  const float* x   = (const float*)d_in[0];
  const float* gw1 = (const float*)d_in[1];
  const float* gb1 = (const float*)d_in[2];
  const float* gw2 = (const float*)d_in[3];
  const float* gb2 = (const float*)d_in[4];
  const float* we1 = (const float*)d_in[5];
  const float* be1 = (const float*)d_in[6];
  const float* we2 = (const float*)d_in[7];
  const float* be2 = (const float*)d_in[8];
  float* out = (float*)d_out;

  char* ws = (char*)d_ws;
  const size_t MiB = 1024 * 1024;
  unsigned short* we1T = (unsigned short*)(ws);                 // 8 MiB
  unsigned short* we2T = (unsigned short*)(ws + 8 * MiB);       // 8 MiB
  int*   pair_tok = (int*)  (ws + 16 * MiB);                    // 2 MiB
  float* pair_w   = (float*)(ws + 18 * MiB);                    // 2 MiB
  int*   counts   = (int*)  (ws + 20 * MiB);                    // 64 B
  int*   offs     = (int*)  (ws + 20 * MiB + 256);              // 64 B
  unsigned short* xbf = (unsigned short*)(ws + 21 * MiB);       // 64 MiB
  float* hbuf     = (float*)(ws + 85 * MiB);                    // 64 MiB
  const bool have_xbf = ws_size >= 86 * MiB;
  const bool have_h   = ws_size >= 150 * MiB;

  hipMemsetAsync(d_out, 0, (size_t)out_size * sizeof(float), stream);
  hipMemsetAsync(counts, 0, 256, stream);

  if (have_xbf)
    hipLaunchKernelGGL(xcvt_kernel, dim3(16384), dim3(256), 0, stream, x, xbf);
  hipLaunchKernelGGL(transpose_cvt_kernel, dim3(1024), dim3(256), 0, stream,
                     we1, we1T, 512, 1024);
  hipLaunchKernelGGL(transpose_cvt_kernel, dim3(1024), dim3(256), 0, stream,
                     we2, we2T, 1024, 512);
  if (have_h){
    hipLaunchKernelGGL(gate_gemm1_kernel, dim3(1024), dim3(256), 0, stream,
                       x, gw1, gb1, hbuf);
    hipLaunchKernelGGL(gate2_kernel, dim3(256), dim3(256), 0, stream,
                       hbuf, gw2, gb2, counts, pair_tok, pair_w);
  } else {
    hipLaunchKernelGGL(gate_fused_kernel, dim3(1024), dim3(256), 0, stream,
                       x, gw1, gb1, gw2, gb2, counts, pair_tok, pair_w);
  }
  hipLaunchKernelGGL(scan_kernel, dim3(1), dim3(64), 0, stream, counts, offs);
  hipLaunchKernelGGL(expert_kernel, dim3(1032), dim3(512), 0, stream,
                     x, have_xbf ? xbf : (const unsigned short*)nullptr,
                     we1T, we2T, be1, be2, counts, offs, pair_tok, pair_w, out);
}

// Round 6
// 1484.160 us; speedup vs baseline: 2.7526x; 2.7526x over previous
//
#include <hip/hip_runtime.h>
#include <hip/hip_bf16.h>
#include <math.h>

// MoE: T=65536 tokens, D=512, H=1024, E=8, TOP_K=2.
// R6: gate_gemm1 rewritten spill-proof (32-reg acc, static indexing,
// launch_bounds cap 128). R5's spilling version wrote 8GB of scratch.
// Expert kernel unchanged (counted vmcnt/raw-barrier schedule, R5).

typedef __attribute__((ext_vector_type(8))) short bf16x8;
typedef __attribute__((ext_vector_type(4))) float f32x4;

__device__ __forceinline__ unsigned short f2bf(float f){
  unsigned u = __builtin_bit_cast(unsigned, f);
  u += 0x7FFFu + ((u >> 16) & 1u);          // RNE
  return (unsigned short)(u >> 16);
}

__device__ __forceinline__ bf16x8 cvt8(float4 f0, float4 f1){
  bf16x8 r;
  r[0]=(short)f2bf(f0.x); r[1]=(short)f2bf(f0.y); r[2]=(short)f2bf(f0.z); r[3]=(short)f2bf(f0.w);
  r[4]=(short)f2bf(f1.x); r[5]=(short)f2bf(f1.y); r[6]=(short)f2bf(f1.z); r[7]=(short)f2bf(f1.w);
  return r;
}

__device__ __forceinline__ void gload16(const void* g, void* l){
  __builtin_amdgcn_global_load_lds((const __attribute__((address_space(1))) unsigned int*)g,
                                   (__attribute__((address_space(3))) unsigned int*)l, 16, 0, 0);
}

#define VW2() asm volatile("s_waitcnt vmcnt(2)" ::: "memory")
#define BAR() __builtin_amdgcn_s_barrier()
#define SB0() __builtin_amdgcn_sched_barrier(0)

// ---------------------------------------------------------------------------
// x fp32 -> bf16 cache
// ---------------------------------------------------------------------------
__global__ __launch_bounds__(256)
void xcvt_kernel(const float* __restrict__ x, unsigned short* __restrict__ xbf){
  int i = blockIdx.x * 256 + threadIdx.x;
  const float4 f0 = ((const float4*)x)[(size_t)i * 2];
  const float4 f1 = ((const float4*)x)[(size_t)i * 2 + 1];
  ushort4 o0, o1;
  o0.x = f2bf(f0.x); o0.y = f2bf(f0.y); o0.z = f2bf(f0.z); o0.w = f2bf(f0.w);
  o1.x = f2bf(f1.x); o1.y = f2bf(f1.y); o1.z = f2bf(f1.z); o1.w = f2bf(f1.w);
  ((ushort4*)xbf)[(size_t)i * 2]     = o0;
  ((ushort4*)xbf)[(size_t)i * 2 + 1] = o1;
}

// ---------------------------------------------------------------------------
// Transpose + fp32->bf16 convert:  in [E][R][C] f32  ->  out [E][C][R] bf16
// ---------------------------------------------------------------------------
__global__ __launch_bounds__(256, 4)
void transpose_cvt_kernel(const float* __restrict__ in, unsigned short* __restrict__ out,
                          int R, int C){
  const int tilesR = R >> 6, tilesC = C >> 6;
  const int b = blockIdx.x;
  const int e = b / (tilesR * tilesC);
  const int rem = b % (tilesR * tilesC);
  const int rb = (rem / tilesC) << 6;
  const int cb = (rem % tilesC) << 6;
  const float* src = in + (size_t)e * R * C;
  unsigned short* dst = out + (size_t)e * R * C;
  __shared__ float t[64][65];
  const int r0 = threadIdx.x >> 4;
  const int c4 = (threadIdx.x & 15) << 2;
  #pragma unroll
  for (int p = 0; p < 4; ++p){
    int r = r0 + (p << 4);
    const float4 v = *(const float4*)(src + (size_t)(rb + r) * C + cb + c4);
    t[r][c4+0] = v.x; t[r][c4+1] = v.y; t[r][c4+2] = v.z; t[r][c4+3] = v.w;
  }
  __syncthreads();
  #pragma unroll
  for (int p = 0; p < 4; ++p){
    int cr = r0 + (p << 4);
    ushort4 o;
    o.x = f2bf(t[c4+0][cr]); o.y = f2bf(t[c4+1][cr]);
    o.z = f2bf(t[c4+2][cr]); o.w = f2bf(t[c4+3][cr]);
    *(ushort4*)(dst + (size_t)(cb + cr) * R + rb + c4) = o;
  }
}

// ---------------------------------------------------------------------------
// Gate GEMM1: h = relu(x @ gw1 + gb1), fp32. 1024 blocks x 512 thr x 64 tok.
// Thread (tg=tid>>6 wave, cg=tid&63): 8 tokens x 4 cols = 32 acc regs.
// xv reads: wave-uniform broadcast (free). wv reads: 64 lanes x 16B = 1KB
// contiguous (conflict-free). Stage writes: g1s full-row (free), xs 4-way.
// ---------------------------------------------------------------------------
__global__ __launch_bounds__(512, 4)
void gate_gemm1_kernel(const float* __restrict__ x, const float* __restrict__ gw1,
                       const float* __restrict__ gb1, float* __restrict__ h){
  __shared__ float xs[32][68];          // [k][tok], pad 68
  __shared__ float g1s[32][256];        // [k][col]
  const int tid = threadIdx.x;
  const int t0 = blockIdx.x << 6;
  const int tg = tid >> 6;              // wave = token group (8 tokens)
  const int cg = tid & 63;              // 4 cols: 4cg..4cg+3

  const int xtok = tid >> 3, xk4 = (tid & 7) << 2;   // x stage: 2 rows/wave
  const int gr = tid >> 6, gc = (tid & 63) << 2;     // gw1 stage

  float acc0[4] = {0.f,0.f,0.f,0.f}, acc1[4] = {0.f,0.f,0.f,0.f};
  float acc2[4] = {0.f,0.f,0.f,0.f}, acc3[4] = {0.f,0.f,0.f,0.f};
  float acc4[4] = {0.f,0.f,0.f,0.f}, acc5[4] = {0.f,0.f,0.f,0.f};
  float acc6[4] = {0.f,0.f,0.f,0.f}, acc7[4] = {0.f,0.f,0.f,0.f};

  for (int kb = 0; kb < 512; kb += 32){
    __syncthreads();                    // protect prev slice reads
    { // stage x: 64 tok x 32 k (transposed scalar writes, pad -> ~4-way)
      const float4 v = *(const float4*)(x + (size_t)(t0 + xtok) * 512 + kb + xk4);
      xs[xk4+0][xtok] = v.x; xs[xk4+1][xtok] = v.y;
      xs[xk4+2][xtok] = v.z; xs[xk4+3][xtok] = v.w;
    }
    #pragma unroll
    for (int p = 0; p < 4; ++p)         // stage gw1: 32 k x 256 col
      *(float4*)&g1s[(p << 3) + gr][gc] =
        *(const float4*)(gw1 + (size_t)(kb + (p << 3) + gr) * 256 + gc);
    __syncthreads();
    #pragma unroll 4
    for (int k = 0; k < 32; ++k){
      const float4 wv = *(const float4*)&g1s[k][cg << 2];
      const float4 xa = *(const float4*)&xs[k][tg << 3];
      const float4 xb = *(const float4*)&xs[k][(tg << 3) + 4];
      acc0[0]=fmaf(xa.x,wv.x,acc0[0]); acc0[1]=fmaf(xa.x,wv.y,acc0[1]);
      acc0[2]=fmaf(xa.x,wv.z,acc0[2]); acc0[3]=fmaf(xa.x,wv.w,acc0[3]);
      acc1[0]=fmaf(xa.y,wv.x,acc1[0]); acc1[1]=fmaf(xa.y,wv.y,acc1[1]);
      acc1[2]=fmaf(xa.y,wv.z,acc1[2]); acc1[3]=fmaf(xa.y,wv.w,acc1[3]);
      acc2[0]=fmaf(xa.z,wv.x,acc2[0]); acc2[1]=fmaf(xa.z,wv.y,acc2[1]);
      acc2[2]=fmaf(xa.z,wv.z,acc2[2]); acc2[3]=fmaf(xa.z,wv.w,acc2[3]);
      acc3[0]=fmaf(xa.w,wv.x,acc3[0]); acc3[1]=fmaf(xa.w,wv.y,acc3[1]);
      acc3[2]=fmaf(xa.w,wv.z,acc3[2]); acc3[3]=fmaf(xa.w,wv.w,acc3[3]);
      acc4[0]=fmaf(xb.x,wv.x,acc4[0]); acc4[1]=fmaf(xb.x,wv.y,acc4[1]);
      acc4[2]=fmaf(xb.x,wv.z,acc4[2]); acc4[3]=fmaf(xb.x,wv.w,acc4[3]);
      acc5[0]=fmaf(xb.y,wv.x,acc5[0]); acc5[1]=fmaf(xb.y,wv.y,acc5[1]);
      acc5[2]=fmaf(xb.y,wv.z,acc5[2]); acc5[3]=fmaf(xb.y,wv.w,acc5[3]);
      acc6[0]=fmaf(xb.z,wv.x,acc6[0]); acc6[1]=fmaf(xb.z,wv.y,acc6[1]);
      acc6[2]=fmaf(xb.z,wv.z,acc6[2]); acc6[3]=fmaf(xb.z,wv.w,acc6[3]);
      acc7[0]=fmaf(xb.w,wv.x,acc7[0]); acc7[1]=fmaf(xb.w,wv.y,acc7[1]);
      acc7[2]=fmaf(xb.w,wv.z,acc7[2]); acc7[3]=fmaf(xb.w,wv.w,acc7[3]);
    }
  }

  const float4 bias = *(const float4*)(gb1 + (cg << 2));
  float* hp = h + (size_t)(t0 + (tg << 3)) * 256 + (cg << 2);
  float4 o;
  #define HOUT(ACC, T) \
    o.x = fmaxf(ACC[0] + bias.x, 0.f); o.y = fmaxf(ACC[1] + bias.y, 0.f); \
    o.z = fmaxf(ACC[2] + bias.z, 0.f); o.w = fmaxf(ACC[3] + bias.w, 0.f); \
    *(float4*)(hp + (size_t)(T) * 256) = o;
  HOUT(acc0, 0) HOUT(acc1, 1) HOUT(acc2, 2) HOUT(acc3, 3)
  HOUT(acc4, 4) HOUT(acc5, 5) HOUT(acc6, 6) HOUT(acc7, 7)
  #undef HOUT
}

// ---------------------------------------------------------------------------
// Gate2: logits = h @ gw2 + gb2; softmax; top2; re-softmax; block-aggregated
// scatter (LDS lists, 8 global atomics per block). 256 blocks x 256 thr.
// ---------------------------------------------------------------------------
__global__ __launch_bounds__(256, 2)
void gate2_kernel(const float* __restrict__ h, const float* __restrict__ gw2,
                  const float* __restrict__ gb2,
                  int* __restrict__ counts, int* __restrict__ pair_tok,
                  float* __restrict__ pair_w){
  __shared__ float g2s[256 * 9];
  __shared__ int   lcnt[8];
  __shared__ int   lbase[8];
  __shared__ int   lpre[9];
  __shared__ int   ltok[8][256];
  __shared__ float lw[8][256];
  const int tid = threadIdx.x;
  const int t0 = blockIdx.x << 8;

  #pragma unroll
  for (int p = 0; p < 8; ++p){
    int idx = tid + (p << 8);
    g2s[(idx >> 3) * 9 + (idx & 7)] = gw2[idx];
  }
  if (tid < 8) lcnt[tid] = 0;
  __syncthreads();

  const int token = t0 + tid;
  float pl[8];
  #pragma unroll
  for (int e = 0; e < 8; ++e) pl[e] = gb2[e];
  for (int j = 0; j < 64; ++j){
    const float4 hv = *(const float4*)(h + (size_t)token * 256 + (j << 2));
    #pragma unroll
    for (int i = 0; i < 4; ++i){
      const float hx = ((const float*)&hv)[i];
      #pragma unroll
      for (int e = 0; e < 8; ++e)
        pl[e] = fmaf(hx, g2s[((j << 2) + i) * 9 + e], pl[e]);
    }
  }
  float m = pl[0];
  #pragma unroll
  for (int e = 1; e < 8; ++e) m = fmaxf(m, pl[e]);
  float p[8]; float s = 0.f;
  #pragma unroll
  for (int e = 0; e < 8; ++e){ p[e] = expf(pl[e] - m); s += p[e]; }
  float inv = 1.f / s;
  float m1 = -1.f, m2 = -1.f; int i1 = 0, i2 = 0;
  #pragma unroll
  for (int e = 0; e < 8; ++e){
    float pe = p[e] * inv;
    if (pe > m1){ m2 = m1; i2 = i1; m1 = pe; i1 = e; }
    else if (pe > m2){ m2 = pe; i2 = e; }
  }
  float e21 = expf(m2 - m1);
  float w1 = 1.f / (1.f + e21);
  float w2 = 1.f - w1;
  int p1 = atomicAdd(&lcnt[i1], 1); ltok[i1][p1] = token; lw[i1][p1] = w1;
  int p2 = atomicAdd(&lcnt[i2], 1); ltok[i2][p2] = token; lw[i2][p2] = w2;
  __syncthreads();
  if (tid < 8) lbase[tid] = atomicAdd(&counts[tid], lcnt[tid]);
  if (tid == 0){
    lpre[0] = 0;
    #pragma unroll
    for (int e = 0; e < 8; ++e) lpre[e+1] = lpre[e] + lcnt[e];
  }
  __syncthreads();
  const int total = lpre[8];
  for (int idx = tid; idx < total; idx += 256){
    int e = 0;
    #pragma unroll
    for (int q = 0; q < 7; ++q) e += (idx >= lpre[q + 1]) ? 1 : 0;
    const int i = idx - lpre[e];
    const int dst = (e << 16) + lbase[e] + i;
    pair_tok[dst] = ltok[e][i];
    pair_w[dst]   = lw[e][i];
  }
}

// ---------------------------------------------------------------------------
// Chunk scan
// ---------------------------------------------------------------------------
__global__ void scan_kernel(const int* __restrict__ counts, int* __restrict__ offs){
  if (threadIdx.x == 0){
    int o = 0;
    #pragma unroll
    for (int e = 0; e < 8; ++e){ offs[e] = o; o += (counts[e] + 127) >> 7; }
    offs[8] = o;
  }
}

// ---------------------------------------------------------------------------
// Expert MLP (unchanged from R5). Compacted grid. 512 thr = 8 waves.
// Phase = { issue stage; s_waitcnt vmcnt(2); s_barrier; 16 MFMA; s_barrier }.
// ---------------------------------------------------------------------------
#define G1_MFMA(S, BUF) do{ \
  __builtin_amdgcn_s_setprio(1); \
  _Pragma("unroll") \
  for (int ct = 0; ct < 4; ++ct){ \
    const int col = (ct << 4) + lrow; \
    const int swc = (col & 7) << 4; \
    _Pragma("unroll") \
    for (int k2 = 0; k2 < 4; ++k2){ \
      const int byt = (col << 8) + ((((k2) << 6) + (kgrp << 4)) ^ swc); \
      bf16x8 bfr = *(const bf16x8*)((const char*)(BUF) + byt); \
      hacc[ct] = __builtin_amdgcn_mfma_f32_16x16x32_bf16(a[(S)*4 + k2], bfr, hacc[ct], 0, 0, 0); \
    } \
  } \
  __builtin_amdgcn_s_setprio(0); \
}while(0)

#define G2_MFMA(NB, BUF) do{ \
  __builtin_amdgcn_s_setprio(1); \
  _Pragma("unroll") \
  for (int nt = 0; nt < 8; ++nt){ \
    const int col = (nt << 4) + lrow; \
    const int swc = (col & 7) << 4; \
    _Pragma("unroll") \
    for (int k2 = 0; k2 < 2; ++k2){ \
      const int byt = (col << 7) + (((k2 << 6) + (kgrp << 4)) ^ swc); \
      bf16x8 bfr = *(const bf16x8*)((const char*)(BUF) + byt); \
      acc[(NB)*8 + nt] = __builtin_amdgcn_mfma_f32_16x16x32_bf16(a2[k2], bfr, acc[(NB)*8 + nt], 0, 0, 0); \
    } \
  } \
  __builtin_amdgcn_s_setprio(0); \
}while(0)

#define PHASE(STAGE_STMT, MFMA_STMT) do{ \
  STAGE_STMT; VW2(); BAR(); SB0(); MFMA_STMT; SB0(); BAR(); }while(0)

__global__ __launch_bounds__(512, 2)
void expert_kernel(const float* __restrict__ x,
                   const unsigned short* __restrict__ xbf,   // may be null
                   const unsigned short* __restrict__ we1T,  // [E][1024][512] bf16
                   const unsigned short* __restrict__ we2T,  // [E][512][1024] bf16
                   const float* __restrict__ be1, const float* __restrict__ be2,
                   const int* __restrict__ counts, const int* __restrict__ offs,
                   const int* __restrict__ pair_tok, const float* __restrict__ pair_w,
                   float* __restrict__ out){
  const int b = blockIdx.x;
  if (b >= offs[8]) return;
  int e = 0;
  #pragma unroll
  for (int q = 0; q < 7; ++q) e += (b >= offs[q + 1]) ? 1 : 0;
  const int cnt = counts[e];
  const int base = (b - offs[e]) << 7;
  const int tid = threadIdx.x;
  const int wv = tid >> 6;
  const int lane = tid & 63;
  const int lrow = lane & 15;
  const int kgrp = lane >> 4;

  __shared__ unsigned short w1s0[64 * 128];
  __shared__ unsigned short w1s1[64 * 128];
  __shared__ unsigned short w2s0[128 * 64];
  __shared__ unsigned short w2s1[128 * 64];
  __shared__ unsigned short hs[128 * 64];

  bf16x8 a[16];
  {
    int r = base + (wv << 4) + lrow;
    int tok = (r < cnt) ? pair_tok[(e << 16) + r] : 0;
    if (xbf){
      const unsigned short* xr = xbf + (size_t)tok * 512 + (kgrp << 3);
      #pragma unroll
      for (int kc = 0; kc < 16; ++kc)
        a[kc] = *(const bf16x8*)(xr + (kc << 5));
    } else {
      const float* xr = x + (size_t)tok * 512 + (kgrp << 3);
      #pragma unroll
      for (int kc = 0; kc < 16; ++kc){
        const float4 f0 = *(const float4*)(xr + (kc << 5));
        const float4 f1 = *(const float4*)(xr + (kc << 5) + 4);
        a[kc] = cvt8(f0, f1);
      }
    }
  }
  f32x4 acc[32];
  #pragma unroll
  for (int i = 0; i < 32; ++i) acc[i] = (f32x4)0.f;

  const unsigned short* w1g = we1T + ((size_t)e << 19);
  const unsigned short* w2g = we2T + ((size_t)e << 19);

  auto stage_w1 = [&](int hcv, int s, unsigned short* buf){
    #pragma unroll
    for (int i = 0; i < 2; ++i){
      int bb = (((wv << 1) + i) << 10) + (lane << 4);
      int row = bb >> 8;
      int inner = bb & 255;
      int srcb = ((hcv + row) << 10) + (s << 8) + (inner ^ ((row & 7) << 4));
      gload16((const char*)w1g + srcb, (char*)buf + (((wv << 1) + i) << 10));
    }
  };
  auto stage_w2 = [&](int hcv, int nb, unsigned short* buf){
    #pragma unroll
    for (int i = 0; i < 2; ++i){
      int bb = (((wv << 1) + i) << 10) + (lane << 4);
      int row = bb >> 7;
      int inner = bb & 127;
      int srcb = (((nb << 7) + row) << 11) + (hcv << 1) + (inner ^ ((row & 7) << 4));
      gload16((const char*)w2g + srcb, (char*)buf + (((wv << 1) + i) << 10));
    }
  };

  stage_w1(0, 0, w1s0);

  for (int hc = 0; hc < 1024; hc += 64){
    f32x4 hacc[4];
    #pragma unroll
    for (int i = 0; i < 4; ++i) hacc[i] = (f32x4)0.f;

    PHASE(stage_w1(hc, 1, w1s1), G1_MFMA(0, w1s0));
    PHASE(stage_w1(hc, 2, w1s0), G1_MFMA(1, w1s1));
    PHASE(stage_w1(hc, 3, w1s1), G1_MFMA(2, w1s0));
    PHASE(stage_w2(hc, 0, w2s0), G1_MFMA(3, w1s1));

    // gelu + store h (wave-local rows; no barrier needed) + read a2
    bf16x8 a2[2];
    {
      char* const hsb = (char*)hs;
      #pragma unroll
      for (int ct = 0; ct < 4; ++ct){
        int colL = (ct << 4) + lrow;
        float bias = be1[(e << 10) + hc + colL];
        #pragma unroll
        for (int rr = 0; rr < 4; ++rr){
          int rowL = (wv << 4) + (kgrp << 2) + rr;
          float v = hacc[ct][rr] + bias;
          float g = 0.5f * v * (1.f + erff(v * 0.70710678118654752f));
          int byt = (rowL << 7) + (colL << 1);
          *(unsigned short*)(hsb + (byt ^ ((rowL & 7) << 4))) = f2bf(g);
        }
      }
      const char* const hsc = (const char*)hs;
      int rowL = (wv << 4) + lrow;
      int swr = (rowL & 7) << 4;
      #pragma unroll
      for (int k2 = 0; k2 < 2; ++k2){
        int byt = (rowL << 7) + (((k2 << 6) + (kgrp << 4)) ^ swr);
        a2[k2] = *(const bf16x8*)(hsc + byt);
      }
    }

    PHASE(stage_w2(hc, 1, w2s1),               G2_MFMA(0, w2s0));
    PHASE(stage_w2(hc, 2, w2s0),               G2_MFMA(1, w2s1));
    PHASE(stage_w2(hc, 3, w2s1),               G2_MFMA(2, w2s0));
    PHASE(stage_w1((hc + 64) & 1023, 0, w1s0), G2_MFMA(3, w2s1));
  }

  // epilogue: weighted atomic accumulate
  #pragma unroll
  for (int rr = 0; rr < 4; ++rr){
    int rowL = (wv << 4) + (kgrp << 2) + rr;
    int rg = base + rowL;
    if (rg < cnt){
      int tok = pair_tok[(e << 16) + rg];
      float wp = pair_w[(e << 16) + rg];
      float* orow = out + (size_t)tok * 512;
      #pragma unroll
      for (int tl = 0; tl < 32; ++tl){
        int col = (tl << 4) + lrow;
        atomicAdd(orow + col, wp * (acc[tl][rr] + be2[(e << 9) + col]));
      }
    }
  }
}

// ---------------------------------------------------------------------------
// Fallback fused gate (only if ws too small for h buffer).
// ---------------------------------------------------------------------------
__global__ __launch_bounds__(256, 3)
void gate_fused_kernel(const float* __restrict__ x, const float* __restrict__ gw1,
                       const float* __restrict__ gb1, const float* __restrict__ gw2,
                       const float* __restrict__ gb2,
                       int* __restrict__ counts, int* __restrict__ pair_tok,
                       float* __restrict__ pair_w){
  __shared__ float xs[16][68];
  __shared__ float g1s[16][256];
  __shared__ float g2s[256 * 9];
  __shared__ float b1s[256];
  const int tid = threadIdx.x;
  const int t0 = blockIdx.x << 6;
  const int tg = tid >> 5, cg = tid & 31;
  #pragma unroll
  for (int p = 0; p < 8; ++p){
    int idx = tid + (p << 8);
    g2s[(idx >> 3) * 9 + (idx & 7)] = gw2[idx];
  }
  b1s[tid] = gb1[tid];
  float acc[8][8];
  #pragma unroll
  for (int t = 0; t < 8; ++t)
    #pragma unroll
    for (int j = 0; j < 8; ++j) acc[t][j] = 0.f;
  for (int kb = 0; kb < 512; kb += 16){
    __syncthreads();
    {
      int r = tid >> 2, c = (tid & 3) << 2;
      const float4 v = *(const float4*)(x + (size_t)(t0 + r) * 512 + kb + c);
      xs[c+0][r] = v.x; xs[c+1][r] = v.y; xs[c+2][r] = v.z; xs[c+3][r] = v.w;
    }
    #pragma unroll
    for (int p = 0; p < 4; ++p){
      int f = tid + (p << 8);
      int r = f >> 6, c4 = (f & 63) << 2;
      *(float4*)&g1s[r][c4] = *(const float4*)(gw1 + (size_t)(kb + r) * 256 + c4);
    }
    __syncthreads();
    #pragma unroll
    for (int k = 0; k < 16; ++k){
      float xv[8], wv[8];
      *(float4*)&xv[0] = *(const float4*)&xs[k][tg << 3];
      *(float4*)&xv[4] = *(const float4*)&xs[k][(tg << 3) + 4];
      *(float4*)&wv[0] = *(const float4*)&g1s[k][cg << 2];
      *(float4*)&wv[4] = *(const float4*)&g1s[k][128 + (cg << 2)];
      #pragma unroll
      for (int t = 0; t < 8; ++t)
        #pragma unroll
        for (int j = 0; j < 8; ++j)
          acc[t][j] = fmaf(xv[t], wv[j], acc[t][j]);
    }
  }
  float pl[8][8];
  #pragma unroll
  for (int t = 0; t < 8; ++t)
    #pragma unroll
    for (int e = 0; e < 8; ++e) pl[t][e] = 0.f;
  #pragma unroll
  for (int j = 0; j < 8; ++j){
    int col = (j < 4) ? ((cg << 2) + j) : (128 + (cg << 2) + j - 4);
    float bias = b1s[col];
    #pragma unroll
    for (int t = 0; t < 8; ++t){
      float hv = fmaxf(acc[t][j] + bias, 0.f);
      #pragma unroll
      for (int e = 0; e < 8; ++e)
        pl[t][e] = fmaf(hv, g2s[col * 9 + e], pl[t][e]);
    }
  }
  #pragma unroll
  for (int m = 1; m <= 16; m <<= 1)
    #pragma unroll
    for (int t = 0; t < 8; ++t)
      #pragma unroll
      for (int e = 0; e < 8; ++e)
        pl[t][e] += __shfl_xor(pl[t][e], m, 64);
  if (cg == 0){
    #pragma unroll
    for (int t = 0; t < 8; ++t){
      int token = t0 + (tg << 3) + t;
      float lg[8];
      #pragma unroll
      for (int e = 0; e < 8; ++e) lg[e] = pl[t][e] + gb2[e];
      float m = lg[0];
      #pragma unroll
      for (int e = 1; e < 8; ++e) m = fmaxf(m, lg[e]);
      float p[8]; float s = 0.f;
      #pragma unroll
      for (int e = 0; e < 8; ++e){ p[e] = expf(lg[e] - m); s += p[e]; }
      float inv = 1.f / s;
      float m1 = -1.f, m2 = -1.f; int i1 = 0, i2 = 0;
      #pragma unroll
      for (int e = 0; e < 8; ++e){
        float pe = p[e] * inv;
        if (pe > m1){ m2 = m1; i2 = i1; m1 = pe; i1 = e; }
        else if (pe > m2){ m2 = pe; i2 = e; }
      }
      float e21 = expf(m2 - m1);
      float w1 = 1.f / (1.f + e21);
      float w2 = 1.f - w1;
      int pos1 = atomicAdd(&counts[i1], 1);
      pair_tok[(i1 << 16) + pos1] = token; pair_w[(i1 << 16) + pos1] = w1;
      int pos2 = atomicAdd(&counts[i2], 1);
      pair_tok[(i2 << 16) + pos2] = token; pair_w[(i2 << 16) + pos2] = w2;
    }
  }
}

// ---------------------------------------------------------------------------
extern "C" void kernel_launch(void* const* d_in, const int* in_sizes, int n_in,
                              void* d_out, int out_size, void* d_ws, size_t ws_size,
                              hipStream_t stream){
  const float* x   = (const float*)d_in[0];
  const float* gw1 = (const float*)d_in[1];
  const float* gb1 = (const float*)d_in[2];
  const float* gw2 = (const float*)d_in[3];
  const float* gb2 = (const float*)d_in[4];
  const float* we1 = (const float*)d_in[5];
  const float* be1 = (const float*)d_in[6];
  const float* we2 = (const float*)d_in[7];
  const float* be2 = (const float*)d_in[8];
  float* out = (float*)d_out;

  char* ws = (char*)d_ws;
  const size_t MiB = 1024 * 1024;
  unsigned short* we1T = (unsigned short*)(ws);                 // 8 MiB
  unsigned short* we2T = (unsigned short*)(ws + 8 * MiB);       // 8 MiB
  int*   pair_tok = (int*)  (ws + 16 * MiB);                    // 2 MiB
  float* pair_w   = (float*)(ws + 18 * MiB);                    // 2 MiB
  int*   counts   = (int*)  (ws + 20 * MiB);                    // 64 B
  int*   offs     = (int*)  (ws + 20 * MiB + 256);              // 64 B
  unsigned short* xbf = (unsigned short*)(ws + 21 * MiB);       // 64 MiB
  float* hbuf     = (float*)(ws + 85 * MiB);                    // 64 MiB
  const bool have_xbf = ws_size >= 86 * MiB;
  const bool have_h   = ws_size >= 150 * MiB;

  hipMemsetAsync(d_out, 0, (size_t)out_size * sizeof(float), stream);
  hipMemsetAsync(counts, 0, 256, stream);

  if (have_xbf)
    hipLaunchKernelGGL(xcvt_kernel, dim3(16384), dim3(256), 0, stream, x, xbf);
  hipLaunchKernelGGL(transpose_cvt_kernel, dim3(1024), dim3(256), 0, stream,
                     we1, we1T, 512, 1024);
  hipLaunchKernelGGL(transpose_cvt_kernel, dim3(1024), dim3(256), 0, stream,
                     we2, we2T, 1024, 512);
  if (have_h){
    hipLaunchKernelGGL(gate_gemm1_kernel, dim3(1024), dim3(512), 0, stream,
                       x, gw1, gb1, hbuf);
    hipLaunchKernelGGL(gate2_kernel, dim3(256), dim3(256), 0, stream,
                       hbuf, gw2, gb2, counts, pair_tok, pair_w);
  } else {
    hipLaunchKernelGGL(gate_fused_kernel, dim3(1024), dim3(256), 0, stream,
                       x, gw1, gb1, gw2, gb2, counts, pair_tok, pair_w);
  }
  hipLaunchKernelGGL(scan_kernel, dim3(1), dim3(64), 0, stream, counts, offs);
  hipLaunchKernelGGL(expert_kernel, dim3(1032), dim3(512), 0, stream,
                     x, have_xbf ? xbf : (const unsigned short*)nullptr,
                     we1T, we2T, be1, be2, counts, offs, pair_tok, pair_w, out);
}

// Round 7
// 968.905 us; speedup vs baseline: 4.2164x; 1.5318x over previous
//
#include <hip/hip_runtime.h>
#include <hip/hip_bf16.h>
#include <math.h>

// MoE: T=65536 tokens, D=512, H=1024, E=8, TOP_K=2.
// R7: expert MLP split into two register-reuse GEMMs (eg1: x->h with gelu,
// eg2: h->out with weighted atomic scatter) through a bf16 h buffer in ws.
// Each GEMM: 128x128 tile, 4 waves of 64x64 (M_rep=N_rep=4 -> 0.5 LDS
// reads/MFMA), 32KB LDS -> 4 blocks/CU. Fallback to R6 fused expert if ws
// is too small for h.

typedef __attribute__((ext_vector_type(8))) short bf16x8;
typedef __attribute__((ext_vector_type(4))) float f32x4;

__device__ __forceinline__ unsigned short f2bf(float f){
  unsigned u = __builtin_bit_cast(unsigned, f);
  u += 0x7FFFu + ((u >> 16) & 1u);          // RNE
  return (unsigned short)(u >> 16);
}

__device__ __forceinline__ bf16x8 cvt8(float4 f0, float4 f1){
  bf16x8 r;
  r[0]=(short)f2bf(f0.x); r[1]=(short)f2bf(f0.y); r[2]=(short)f2bf(f0.z); r[3]=(short)f2bf(f0.w);
  r[4]=(short)f2bf(f1.x); r[5]=(short)f2bf(f1.y); r[6]=(short)f2bf(f1.z); r[7]=(short)f2bf(f1.w);
  return r;
}

__device__ __forceinline__ void gload16(const void* g, void* l){
  __builtin_amdgcn_global_load_lds((const __attribute__((address_space(1))) unsigned int*)g,
                                   (__attribute__((address_space(3))) unsigned int*)l, 16, 0, 0);
}

// ---------------------------------------------------------------------------
// x fp32 -> bf16 cache
// ---------------------------------------------------------------------------
__global__ __launch_bounds__(256)
void xcvt_kernel(const float* __restrict__ x, unsigned short* __restrict__ xbf){
  int i = blockIdx.x * 256 + threadIdx.x;
  const float4 f0 = ((const float4*)x)[(size_t)i * 2];
  const float4 f1 = ((const float4*)x)[(size_t)i * 2 + 1];
  ushort4 o0, o1;
  o0.x = f2bf(f0.x); o0.y = f2bf(f0.y); o0.z = f2bf(f0.z); o0.w = f2bf(f0.w);
  o1.x = f2bf(f1.x); o1.y = f2bf(f1.y); o1.z = f2bf(f1.z); o1.w = f2bf(f1.w);
  ((ushort4*)xbf)[(size_t)i * 2]     = o0;
  ((ushort4*)xbf)[(size_t)i * 2 + 1] = o1;
}

// ---------------------------------------------------------------------------
// Transpose + fp32->bf16 convert:  in [E][R][C] f32  ->  out [E][C][R] bf16
// ---------------------------------------------------------------------------
__global__ __launch_bounds__(256, 4)
void transpose_cvt_kernel(const float* __restrict__ in, unsigned short* __restrict__ out,
                          int R, int C){
  const int tilesR = R >> 6, tilesC = C >> 6;
  const int b = blockIdx.x;
  const int e = b / (tilesR * tilesC);
  const int rem = b % (tilesR * tilesC);
  const int rb = (rem / tilesC) << 6;
  const int cb = (rem % tilesC) << 6;
  const float* src = in + (size_t)e * R * C;
  unsigned short* dst = out + (size_t)e * R * C;
  __shared__ float t[64][65];
  const int r0 = threadIdx.x >> 4;
  const int c4 = (threadIdx.x & 15) << 2;
  #pragma unroll
  for (int p = 0; p < 4; ++p){
    int r = r0 + (p << 4);
    const float4 v = *(const float4*)(src + (size_t)(rb + r) * C + cb + c4);
    t[r][c4+0] = v.x; t[r][c4+1] = v.y; t[r][c4+2] = v.z; t[r][c4+3] = v.w;
  }
  __syncthreads();
  #pragma unroll
  for (int p = 0; p < 4; ++p){
    int cr = r0 + (p << 4);
    ushort4 o;
    o.x = f2bf(t[c4+0][cr]); o.y = f2bf(t[c4+1][cr]);
    o.z = f2bf(t[c4+2][cr]); o.w = f2bf(t[c4+3][cr]);
    *(ushort4*)(dst + (size_t)(cb + cr) * R + rb + c4) = o;
  }
}

// ---------------------------------------------------------------------------
// Gate GEMM1 (fp32, spill-proof, R6): h = relu(x @ gw1 + gb1) -> ghuf
// ---------------------------------------------------------------------------
__global__ __launch_bounds__(512, 4)
void gate_gemm1_kernel(const float* __restrict__ x, const float* __restrict__ gw1,
                       const float* __restrict__ gb1, float* __restrict__ h){
  __shared__ float xs[32][68];
  __shared__ float g1s[32][256];
  const int tid = threadIdx.x;
  const int t0 = blockIdx.x << 6;
  const int tg = tid >> 6;
  const int cg = tid & 63;

  const int xtok = tid >> 3, xk4 = (tid & 7) << 2;
  const int gr = tid >> 6, gc = (tid & 63) << 2;

  float acc0[4] = {0.f,0.f,0.f,0.f}, acc1[4] = {0.f,0.f,0.f,0.f};
  float acc2[4] = {0.f,0.f,0.f,0.f}, acc3[4] = {0.f,0.f,0.f,0.f};
  float acc4[4] = {0.f,0.f,0.f,0.f}, acc5[4] = {0.f,0.f,0.f,0.f};
  float acc6[4] = {0.f,0.f,0.f,0.f}, acc7[4] = {0.f,0.f,0.f,0.f};

  for (int kb = 0; kb < 512; kb += 32){
    __syncthreads();
    {
      const float4 v = *(const float4*)(x + (size_t)(t0 + xtok) * 512 + kb + xk4);
      xs[xk4+0][xtok] = v.x; xs[xk4+1][xtok] = v.y;
      xs[xk4+2][xtok] = v.z; xs[xk4+3][xtok] = v.w;
    }
    #pragma unroll
    for (int p = 0; p < 4; ++p)
      *(float4*)&g1s[(p << 3) + gr][gc] =
        *(const float4*)(gw1 + (size_t)(kb + (p << 3) + gr) * 256 + gc);
    __syncthreads();
    #pragma unroll 4
    for (int k = 0; k < 32; ++k){
      const float4 wv = *(const float4*)&g1s[k][cg << 2];
      const float4 xa = *(const float4*)&xs[k][tg << 3];
      const float4 xb = *(const float4*)&xs[k][(tg << 3) + 4];
      acc0[0]=fmaf(xa.x,wv.x,acc0[0]); acc0[1]=fmaf(xa.x,wv.y,acc0[1]);
      acc0[2]=fmaf(xa.x,wv.z,acc0[2]); acc0[3]=fmaf(xa.x,wv.w,acc0[3]);
      acc1[0]=fmaf(xa.y,wv.x,acc1[0]); acc1[1]=fmaf(xa.y,wv.y,acc1[1]);
      acc1[2]=fmaf(xa.y,wv.z,acc1[2]); acc1[3]=fmaf(xa.y,wv.w,acc1[3]);
      acc2[0]=fmaf(xa.z,wv.x,acc2[0]); acc2[1]=fmaf(xa.z,wv.y,acc2[1]);
      acc2[2]=fmaf(xa.z,wv.z,acc2[2]); acc2[3]=fmaf(xa.z,wv.w,acc2[3]);
      acc3[0]=fmaf(xa.w,wv.x,acc3[0]); acc3[1]=fmaf(xa.w,wv.y,acc3[1]);
      acc3[2]=fmaf(xa.w,wv.z,acc3[2]); acc3[3]=fmaf(xa.w,wv.w,acc3[3]);
      acc4[0]=fmaf(xb.x,wv.x,acc4[0]); acc4[1]=fmaf(xb.x,wv.y,acc4[1]);
      acc4[2]=fmaf(xb.x,wv.z,acc4[2]); acc4[3]=fmaf(xb.x,wv.w,acc4[3]);
      acc5[0]=fmaf(xb.y,wv.x,acc5[0]); acc5[1]=fmaf(xb.y,wv.y,acc5[1]);
      acc5[2]=fmaf(xb.y,wv.z,acc5[2]); acc5[3]=fmaf(xb.y,wv.w,acc5[3]);
      acc6[0]=fmaf(xb.z,wv.x,acc6[0]); acc6[1]=fmaf(xb.z,wv.y,acc6[1]);
      acc6[2]=fmaf(xb.z,wv.z,acc6[2]); acc6[3]=fmaf(xb.z,wv.w,acc6[3]);
      acc7[0]=fmaf(xb.w,wv.x,acc7[0]); acc7[1]=fmaf(xb.w,wv.y,acc7[1]);
      acc7[2]=fmaf(xb.w,wv.z,acc7[2]); acc7[3]=fmaf(xb.w,wv.w,acc7[3]);
    }
  }

  const float4 bias = *(const float4*)(gb1 + (cg << 2));
  float* hp = h + (size_t)(t0 + (tg << 3)) * 256 + (cg << 2);
  float4 o;
  #define HOUT(ACC, T) \
    o.x = fmaxf(ACC[0] + bias.x, 0.f); o.y = fmaxf(ACC[1] + bias.y, 0.f); \
    o.z = fmaxf(ACC[2] + bias.z, 0.f); o.w = fmaxf(ACC[3] + bias.w, 0.f); \
    *(float4*)(hp + (size_t)(T) * 256) = o;
  HOUT(acc0, 0) HOUT(acc1, 1) HOUT(acc2, 2) HOUT(acc3, 3)
  HOUT(acc4, 4) HOUT(acc5, 5) HOUT(acc6, 6) HOUT(acc7, 7)
  #undef HOUT
}

// ---------------------------------------------------------------------------
// Gate2 (R6): logits, softmax, top2, re-softmax, block-aggregated scatter.
// ---------------------------------------------------------------------------
__global__ __launch_bounds__(256, 2)
void gate2_kernel(const float* __restrict__ h, const float* __restrict__ gw2,
                  const float* __restrict__ gb2,
                  int* __restrict__ counts, int* __restrict__ pair_tok,
                  float* __restrict__ pair_w){
  __shared__ float g2s[256 * 9];
  __shared__ int   lcnt[8];
  __shared__ int   lbase[8];
  __shared__ int   lpre[9];
  __shared__ int   ltok[8][256];
  __shared__ float lw[8][256];
  const int tid = threadIdx.x;
  const int t0 = blockIdx.x << 8;

  #pragma unroll
  for (int p = 0; p < 8; ++p){
    int idx = tid + (p << 8);
    g2s[(idx >> 3) * 9 + (idx & 7)] = gw2[idx];
  }
  if (tid < 8) lcnt[tid] = 0;
  __syncthreads();

  const int token = t0 + tid;
  float pl[8];
  #pragma unroll
  for (int e = 0; e < 8; ++e) pl[e] = gb2[e];
  for (int j = 0; j < 64; ++j){
    const float4 hv = *(const float4*)(h + (size_t)token * 256 + (j << 2));
    #pragma unroll
    for (int i = 0; i < 4; ++i){
      const float hx = ((const float*)&hv)[i];
      #pragma unroll
      for (int e = 0; e < 8; ++e)
        pl[e] = fmaf(hx, g2s[((j << 2) + i) * 9 + e], pl[e]);
    }
  }
  float m = pl[0];
  #pragma unroll
  for (int e = 1; e < 8; ++e) m = fmaxf(m, pl[e]);
  float p[8]; float s = 0.f;
  #pragma unroll
  for (int e = 0; e < 8; ++e){ p[e] = expf(pl[e] - m); s += p[e]; }
  float inv = 1.f / s;
  float m1 = -1.f, m2 = -1.f; int i1 = 0, i2 = 0;
  #pragma unroll
  for (int e = 0; e < 8; ++e){
    float pe = p[e] * inv;
    if (pe > m1){ m2 = m1; i2 = i1; m1 = pe; i1 = e; }
    else if (pe > m2){ m2 = pe; i2 = e; }
  }
  float e21 = expf(m2 - m1);
  float w1 = 1.f / (1.f + e21);
  float w2 = 1.f - w1;
  int p1 = atomicAdd(&lcnt[i1], 1); ltok[i1][p1] = token; lw[i1][p1] = w1;
  int p2 = atomicAdd(&lcnt[i2], 1); ltok[i2][p2] = token; lw[i2][p2] = w2;
  __syncthreads();
  if (tid < 8) lbase[tid] = atomicAdd(&counts[tid], lcnt[tid]);
  if (tid == 0){
    lpre[0] = 0;
    #pragma unroll
    for (int e = 0; e < 8; ++e) lpre[e+1] = lpre[e] + lcnt[e];
  }
  __syncthreads();
  const int total = lpre[8];
  for (int idx = tid; idx < total; idx += 256){
    int e = 0;
    #pragma unroll
    for (int q = 0; q < 7; ++q) e += (idx >= lpre[q + 1]) ? 1 : 0;
    const int i = idx - lpre[e];
    const int dst = (e << 16) + lbase[e] + i;
    pair_tok[dst] = ltok[e][i];
    pair_w[dst]   = lw[e][i];
  }
}

// ---------------------------------------------------------------------------
// Scan: chunk offsets (128-token chunks) + exact token prefix offsets.
// ---------------------------------------------------------------------------
__global__ void scan_kernel(const int* __restrict__ counts, int* __restrict__ offs,
                            int* __restrict__ toffs){
  if (threadIdx.x == 0){
    int o = 0, t = 0;
    #pragma unroll
    for (int e = 0; e < 8; ++e){
      offs[e] = o; o += (counts[e] + 127) >> 7;
      toffs[e] = t; t += counts[e];
    }
    offs[8] = o; toffs[8] = t;
  }
}

// ---------------------------------------------------------------------------
// eg1: h[seq][1024] = gelu(gather(x) @ we1 + be1), bf16.
// Grid: chunk*8 + ntile. Block 256 thr, 4 waves 2x2; wave tile 64x64
// (4x4 16x16 frags). LDS 32KB: As[128][64] + Bs[128][64], XOR-swizzled via
// pre-swizzled global source (linear LDS dest for global_load_lds).
// ---------------------------------------------------------------------------
__global__ __launch_bounds__(256, 4)
void eg1_kernel(const unsigned short* __restrict__ xbf,
                const unsigned short* __restrict__ we1T,   // [E][1024][512]
                const float* __restrict__ be1,
                const int* __restrict__ counts, const int* __restrict__ offs,
                const int* __restrict__ toffs, const int* __restrict__ pair_tok,
                unsigned short* __restrict__ h){
  const int b = blockIdx.x;
  const int chunk = b >> 3, nt = b & 7;
  if (chunk >= offs[8]) return;
  int e = 0;
  #pragma unroll
  for (int q = 0; q < 7; ++q) e += (chunk >= offs[q+1]) ? 1 : 0;
  const int cnt = counts[e];
  const int base = (chunk - offs[e]) << 7;
  const int n0 = nt << 7;
  const int tid = threadIdx.x;
  const int lane = tid & 63;
  const int wv = tid >> 6;
  const int wr = wv >> 1, wc = wv & 1;
  const int lrow = lane & 15, kgrp = lane >> 4;

  __shared__ char lds[32768];
  char* const As = lds;
  char* const Bs = lds + 16384;

  // staging mapping: thread covers rows {tid>>3 + 32i}, 16B at (tid&7)*16
  const int srow = tid >> 3;
  const int sdelta = ((tid & 7) << 4) ^ ((srow & 7) << 4);
  unsigned aoff[4];
  #pragma unroll
  for (int i = 0; i < 4; ++i){
    int rr = base + srow + (i << 5);
    int tok = (rr < cnt) ? pair_tok[(e << 16) + rr] : 0;
    aoff[i] = ((unsigned)tok) << 10;      // tok * 512 elems * 2B
  }
  const char* const xb  = (const char*)xbf;
  const char* const w1b = (const char*)we1T + ((size_t)e << 20);

  f32x4 acc[4][4];
  #pragma unroll
  for (int i = 0; i < 4; ++i)
    #pragma unroll
    for (int j = 0; j < 4; ++j) acc[i][j] = (f32x4)0.f;

  const int sw = (lrow & 7) << 4;
  for (int kb = 0; kb < 8; ++kb){
    #pragma unroll
    for (int i = 0; i < 4; ++i)
      gload16(xb + aoff[i] + (kb << 7) + sdelta, As + (tid << 4) + (i << 12));
    #pragma unroll
    for (int i = 0; i < 4; ++i)
      gload16(w1b + (size_t)(n0 + srow + (i << 5)) * 1024 + (kb << 7) + sdelta,
              Bs + (tid << 4) + (i << 12));
    __syncthreads();
    #pragma unroll
    for (int s = 0; s < 2; ++s){
      const int kbyte = ((s << 6) + (kgrp << 4)) ^ sw;
      bf16x8 af[4], bf[4];
      #pragma unroll
      for (int f = 0; f < 4; ++f){
        af[f] = *(const bf16x8*)(As + ((wr << 6) + (f << 4) + lrow) * 128 + kbyte);
        bf[f] = *(const bf16x8*)(Bs + ((wc << 6) + (f << 4) + lrow) * 128 + kbyte);
      }
      #pragma unroll
      for (int fr = 0; fr < 4; ++fr)
        #pragma unroll
        for (int fc = 0; fc < 4; ++fc)
          acc[fr][fc] = __builtin_amdgcn_mfma_f32_16x16x32_bf16(af[fr], bf[fc], acc[fr][fc], 0, 0, 0);
    }
    __syncthreads();
  }

  const int hrow0 = toffs[e] + base;
  #pragma unroll
  for (int fc = 0; fc < 4; ++fc){
    const int col = n0 + (wc << 6) + (fc << 4) + lrow;
    const float bias = be1[(e << 10) + col];
    #pragma unroll
    for (int fr = 0; fr < 4; ++fr){
      #pragma unroll
      for (int rg = 0; rg < 4; ++rg){
        const int rloc = (wr << 6) + (fr << 4) + (kgrp << 2) + rg;
        if (base + rloc < cnt){
          float v = acc[fr][fc][rg] + bias;
          float g = 0.5f * v * (1.f + erff(v * 0.70710678118654752f));
          h[(size_t)(hrow0 + rloc) * 1024 + col] = f2bf(g);
        }
      }
    }
  }
}

// ---------------------------------------------------------------------------
// eg2: out[tok] += w * (h @ we2 + be2).  A = h rows (seq-linear, no gather).
// Grid: chunk*4 + ntile. Same tile structure as eg1; K=1024 (16 steps).
// ---------------------------------------------------------------------------
__global__ __launch_bounds__(256, 4)
void eg2_kernel(const unsigned short* __restrict__ h,
                const unsigned short* __restrict__ we2T,   // [E][512][1024]
                const float* __restrict__ be2,
                const int* __restrict__ counts, const int* __restrict__ offs,
                const int* __restrict__ toffs, const int* __restrict__ pair_tok,
                const float* __restrict__ pair_w,
                float* __restrict__ out){
  const int b = blockIdx.x;
  const int chunk = b >> 2, nt = b & 3;
  if (chunk >= offs[8]) return;
  int e = 0;
  #pragma unroll
  for (int q = 0; q < 7; ++q) e += (chunk >= offs[q+1]) ? 1 : 0;
  const int cnt = counts[e];
  const int base = (chunk - offs[e]) << 7;
  const int n0 = nt << 7;
  const int tid = threadIdx.x;
  const int lane = tid & 63;
  const int wv = tid >> 6;
  const int wr = wv >> 1, wc = wv & 1;
  const int lrow = lane & 15, kgrp = lane >> 4;

  __shared__ char lds[32768];
  char* const As = lds;
  char* const Bs = lds + 16384;

  const int srow = tid >> 3;
  const int sdelta = ((tid & 7) << 4) ^ ((srow & 7) << 4);
  const char* const hb  = (const char*)h + (size_t)(toffs[e] + base) * 2048;
  const char* const w2b = (const char*)we2T + ((size_t)e << 20);

  f32x4 acc[4][4];
  #pragma unroll
  for (int i = 0; i < 4; ++i)
    #pragma unroll
    for (int j = 0; j < 4; ++j) acc[i][j] = (f32x4)0.f;

  const int sw = (lrow & 7) << 4;
  for (int kb = 0; kb < 16; ++kb){
    #pragma unroll
    for (int i = 0; i < 4; ++i)
      gload16(hb + (size_t)(srow + (i << 5)) * 2048 + (kb << 7) + sdelta,
              As + (tid << 4) + (i << 12));
    #pragma unroll
    for (int i = 0; i < 4; ++i)
      gload16(w2b + (size_t)(n0 + srow + (i << 5)) * 2048 + (kb << 7) + sdelta,
              Bs + (tid << 4) + (i << 12));
    __syncthreads();
    #pragma unroll
    for (int s = 0; s < 2; ++s){
      const int kbyte = ((s << 6) + (kgrp << 4)) ^ sw;
      bf16x8 af[4], bf[4];
      #pragma unroll
      for (int f = 0; f < 4; ++f){
        af[f] = *(const bf16x8*)(As + ((wr << 6) + (f << 4) + lrow) * 128 + kbyte);
        bf[f] = *(const bf16x8*)(Bs + ((wc << 6) + (f << 4) + lrow) * 128 + kbyte);
      }
      #pragma unroll
      for (int fr = 0; fr < 4; ++fr)
        #pragma unroll
        for (int fc = 0; fc < 4; ++fc)
          acc[fr][fc] = __builtin_amdgcn_mfma_f32_16x16x32_bf16(af[fr], bf[fc], acc[fr][fc], 0, 0, 0);
    }
    __syncthreads();
  }

  float bias2[4];
  #pragma unroll
  for (int fc = 0; fc < 4; ++fc)
    bias2[fc] = be2[(e << 9) + n0 + (wc << 6) + (fc << 4) + lrow];

  #pragma unroll
  for (int fr = 0; fr < 4; ++fr){
    #pragma unroll
    for (int rg = 0; rg < 4; ++rg){
      const int rloc = (wr << 6) + (fr << 4) + (kgrp << 2) + rg;
      const int r = base + rloc;
      if (r < cnt){
        const int tok = pair_tok[(e << 16) + r];
        const float wgt = pair_w[(e << 16) + r];
        float* const orow = out + (size_t)tok * 512 + n0 + (wc << 6) + lrow;
        #pragma unroll
        for (int fc = 0; fc < 4; ++fc)
          atomicAdd(orow + (fc << 4), wgt * (acc[fr][fc][rg] + bias2[fc]));
      }
    }
  }
}

// ---------------------------------------------------------------------------
// Fallback fused expert (R6) - used only if ws too small for h buffer.
// ---------------------------------------------------------------------------
#define VW2() asm volatile("s_waitcnt vmcnt(2)" ::: "memory")
#define BAR() __builtin_amdgcn_s_barrier()
#define SB0() __builtin_amdgcn_sched_barrier(0)

#define G1_MFMA(S, BUF) do{ \
  __builtin_amdgcn_s_setprio(1); \
  _Pragma("unroll") \
  for (int ct = 0; ct < 4; ++ct){ \
    const int col = (ct << 4) + lrow; \
    const int swc = (col & 7) << 4; \
    _Pragma("unroll") \
    for (int k2 = 0; k2 < 4; ++k2){ \
      const int byt = (col << 8) + ((((k2) << 6) + (kgrp << 4)) ^ swc); \
      bf16x8 bfr = *(const bf16x8*)((const char*)(BUF) + byt); \
      hacc[ct] = __builtin_amdgcn_mfma_f32_16x16x32_bf16(a[(S)*4 + k2], bfr, hacc[ct], 0, 0, 0); \
    } \
  } \
  __builtin_amdgcn_s_setprio(0); \
}while(0)

#define G2_MFMA(NB, BUF) do{ \
  __builtin_amdgcn_s_setprio(1); \
  _Pragma("unroll") \
  for (int nt2 = 0; nt2 < 8; ++nt2){ \
    const int col = (nt2 << 4) + lrow; \
    const int swc = (col & 7) << 4; \
    _Pragma("unroll") \
    for (int k2 = 0; k2 < 2; ++k2){ \
      const int byt = (col << 7) + (((k2 << 6) + (kgrp << 4)) ^ swc); \
      bf16x8 bfr = *(const bf16x8*)((const char*)(BUF) + byt); \
      acc[(NB)*8 + nt2] = __builtin_amdgcn_mfma_f32_16x16x32_bf16(a2[k2], bfr, acc[(NB)*8 + nt2], 0, 0, 0); \
    } \
  } \
  __builtin_amdgcn_s_setprio(0); \
}while(0)

#define PHASE(STAGE_STMT, MFMA_STMT) do{ \
  STAGE_STMT; VW2(); BAR(); SB0(); MFMA_STMT; SB0(); BAR(); }while(0)

__global__ __launch_bounds__(512, 2)
void expert_kernel(const unsigned short* __restrict__ xbf,
                   const unsigned short* __restrict__ we1T,
                   const unsigned short* __restrict__ we2T,
                   const float* __restrict__ be1, const float* __restrict__ be2,
                   const int* __restrict__ counts, const int* __restrict__ offs,
                   const int* __restrict__ pair_tok, const float* __restrict__ pair_w,
                   float* __restrict__ out){
  const int b = blockIdx.x;
  if (b >= offs[8]) return;
  int e = 0;
  #pragma unroll
  for (int q = 0; q < 7; ++q) e += (b >= offs[q + 1]) ? 1 : 0;
  const int cnt = counts[e];
  const int base = (b - offs[e]) << 7;
  const int tid = threadIdx.x;
  const int wv = tid >> 6;
  const int lane = tid & 63;
  const int lrow = lane & 15;
  const int kgrp = lane >> 4;

  __shared__ unsigned short w1s0[64 * 128];
  __shared__ unsigned short w1s1[64 * 128];
  __shared__ unsigned short w2s0[128 * 64];
  __shared__ unsigned short w2s1[128 * 64];
  __shared__ unsigned short hs[128 * 64];

  bf16x8 a[16];
  {
    int r = base + (wv << 4) + lrow;
    int tok = (r < cnt) ? pair_tok[(e << 16) + r] : 0;
    const unsigned short* xr = xbf + (size_t)tok * 512 + (kgrp << 3);
    #pragma unroll
    for (int kc = 0; kc < 16; ++kc)
      a[kc] = *(const bf16x8*)(xr + (kc << 5));
  }
  f32x4 acc[32];
  #pragma unroll
  for (int i = 0; i < 32; ++i) acc[i] = (f32x4)0.f;

  const unsigned short* w1g = we1T + ((size_t)e << 19);
  const unsigned short* w2g = we2T + ((size_t)e << 19);

  auto stage_w1 = [&](int hcv, int s, unsigned short* buf){
    #pragma unroll
    for (int i = 0; i < 2; ++i){
      int bb = (((wv << 1) + i) << 10) + (lane << 4);
      int row = bb >> 8;
      int inner = bb & 255;
      int srcb = ((hcv + row) << 10) + (s << 8) + (inner ^ ((row & 7) << 4));
      gload16((const char*)w1g + srcb, (char*)buf + (((wv << 1) + i) << 10));
    }
  };
  auto stage_w2 = [&](int hcv, int nb, unsigned short* buf){
    #pragma unroll
    for (int i = 0; i < 2; ++i){
      int bb = (((wv << 1) + i) << 10) + (lane << 4);
      int row = bb >> 7;
      int inner = bb & 127;
      int srcb = (((nb << 7) + row) << 11) + (hcv << 1) + (inner ^ ((row & 7) << 4));
      gload16((const char*)w2g + srcb, (char*)buf + (((wv << 1) + i) << 10));
    }
  };

  stage_w1(0, 0, w1s0);

  for (int hc = 0; hc < 1024; hc += 64){
    f32x4 hacc[4];
    #pragma unroll
    for (int i = 0; i < 4; ++i) hacc[i] = (f32x4)0.f;

    PHASE(stage_w1(hc, 1, w1s1), G1_MFMA(0, w1s0));
    PHASE(stage_w1(hc, 2, w1s0), G1_MFMA(1, w1s1));
    PHASE(stage_w1(hc, 3, w1s1), G1_MFMA(2, w1s0));
    PHASE(stage_w2(hc, 0, w2s0), G1_MFMA(3, w1s1));

    bf16x8 a2[2];
    {
      char* const hsb = (char*)hs;
      #pragma unroll
      for (int ct = 0; ct < 4; ++ct){
        int colL = (ct << 4) + lrow;
        float bias = be1[(e << 10) + hc + colL];
        #pragma unroll
        for (int rr = 0; rr < 4; ++rr){
          int rowL = (wv << 4) + (kgrp << 2) + rr;
          float v = hacc[ct][rr] + bias;
          float g = 0.5f * v * (1.f + erff(v * 0.70710678118654752f));
          int byt = (rowL << 7) + (colL << 1);
          *(unsigned short*)(hsb + (byt ^ ((rowL & 7) << 4))) = f2bf(g);
        }
      }
      const char* const hsc = (const char*)hs;
      int rowL = (wv << 4) + lrow;
      int swr = (rowL & 7) << 4;
      #pragma unroll
      for (int k2 = 0; k2 < 2; ++k2){
        int byt = (rowL << 7) + (((k2 << 6) + (kgrp << 4)) ^ swr);
        a2[k2] = *(const bf16x8*)(hsc + byt);
      }
    }

    PHASE(stage_w2(hc, 1, w2s1),               G2_MFMA(0, w2s0));
    PHASE(stage_w2(hc, 2, w2s0),               G2_MFMA(1, w2s1));
    PHASE(stage_w2(hc, 3, w2s1),               G2_MFMA(2, w2s0));
    PHASE(stage_w1((hc + 64) & 1023, 0, w1s0), G2_MFMA(3, w2s1));
  }

  #pragma unroll
  for (int rr = 0; rr < 4; ++rr){
    int rowL = (wv << 4) + (kgrp << 2) + rr;
    int rg = base + rowL;
    if (rg < cnt){
      int tok = pair_tok[(e << 16) + rg];
      float wp = pair_w[(e << 16) + rg];
      float* orow = out + (size_t)tok * 512;
      #pragma unroll
      for (int tl = 0; tl < 32; ++tl){
        int col = (tl << 4) + lrow;
        atomicAdd(orow + col, wp * (acc[tl][rr] + be2[(e << 9) + col]));
      }
    }
  }
}

// ---------------------------------------------------------------------------
extern "C" void kernel_launch(void* const* d_in, const int* in_sizes, int n_in,
                              void* d_out, int out_size, void* d_ws, size_t ws_size,
                              hipStream_t stream){
  const float* x   = (const float*)d_in[0];
  const float* gw1 = (const float*)d_in[1];
  const float* gb1 = (const float*)d_in[2];
  const float* gw2 = (const float*)d_in[3];
  const float* gb2 = (const float*)d_in[4];
  const float* we1 = (const float*)d_in[5];
  const float* be1 = (const float*)d_in[6];
  const float* we2 = (const float*)d_in[7];
  const float* be2 = (const float*)d_in[8];
  float* out = (float*)d_out;

  char* ws = (char*)d_ws;
  const size_t MiB = 1024 * 1024;
  unsigned short* we1T = (unsigned short*)(ws);                 // 8 MiB
  unsigned short* we2T = (unsigned short*)(ws + 8 * MiB);       // 8 MiB
  int*   pair_tok = (int*)  (ws + 16 * MiB);                    // 2 MiB
  float* pair_w   = (float*)(ws + 18 * MiB);                    // 2 MiB
  int*   counts   = (int*)  (ws + 20 * MiB);                    // 64 B
  int*   offs     = (int*)  (ws + 20 * MiB + 256);              // 64 B
  int*   toffs    = (int*)  (ws + 20 * MiB + 512);              // 64 B
  unsigned short* xbf  = (unsigned short*)(ws + 21 * MiB);      // 64 MiB
  float* ghuf          = (float*)(ws + 85 * MiB);               // 64 MiB (gate h)
  unsigned short* hexp = (unsigned short*)(ws + 85 * MiB);      // 257 MiB, aliases
                                                                // ghuf (stream-ordered)
  const bool big = ws_size >= 344 * MiB;

  hipMemsetAsync(d_out, 0, (size_t)out_size * sizeof(float), stream);
  hipMemsetAsync(counts, 0, 256, stream);

  hipLaunchKernelGGL(xcvt_kernel, dim3(16384), dim3(256), 0, stream, x, xbf);
  hipLaunchKernelGGL(transpose_cvt_kernel, dim3(1024), dim3(256), 0, stream,
                     we1, we1T, 512, 1024);
  hipLaunchKernelGGL(transpose_cvt_kernel, dim3(1024), dim3(256), 0, stream,
                     we2, we2T, 1024, 512);
  hipLaunchKernelGGL(gate_gemm1_kernel, dim3(1024), dim3(512), 0, stream,
                     x, gw1, gb1, ghuf);
  hipLaunchKernelGGL(gate2_kernel, dim3(256), dim3(256), 0, stream,
                     ghuf, gw2, gb2, counts, pair_tok, pair_w);
  hipLaunchKernelGGL(scan_kernel, dim3(1), dim3(64), 0, stream, counts, offs, toffs);

  if (big){
    hipLaunchKernelGGL(eg1_kernel, dim3(1031 * 8), dim3(256), 0, stream,
                       xbf, we1T, be1, counts, offs, toffs, pair_tok, hexp);
    hipLaunchKernelGGL(eg2_kernel, dim3(1031 * 4), dim3(256), 0, stream,
                       hexp, we2T, be2, counts, offs, toffs, pair_tok, pair_w, out);
  } else {
    hipLaunchKernelGGL(expert_kernel, dim3(1032), dim3(512), 0, stream,
                       xbf, we1T, we2T, be1, be2, counts, offs, pair_tok, pair_w, out);
  }
}

// Round 8
// 799.625 us; speedup vs baseline: 5.1090x; 1.2117x over previous
//
#include <hip/hip_runtime.h>
#include <hip/hip_bf16.h>
#include <math.h>

// MoE: T=65536 tokens, D=512, H=1024, E=8, TOP_K=2.
// R8: eg1/eg2 get XCD-chunked block swizzle (chunk's N-tiles share one XCD's
// L2 -> x/h fetched once, weights resident); eg1 epilogue uses swapped MFMA
// operands so h-stores are 8B ushort4 (was 64 scalar 2B stores/thread).

typedef __attribute__((ext_vector_type(8))) short bf16x8;
typedef __attribute__((ext_vector_type(4))) float f32x4;

__device__ __forceinline__ unsigned short f2bf(float f){
  unsigned u = __builtin_bit_cast(unsigned, f);
  u += 0x7FFFu + ((u >> 16) & 1u);          // RNE
  return (unsigned short)(u >> 16);
}

__device__ __forceinline__ bf16x8 cvt8(float4 f0, float4 f1){
  bf16x8 r;
  r[0]=(short)f2bf(f0.x); r[1]=(short)f2bf(f0.y); r[2]=(short)f2bf(f0.z); r[3]=(short)f2bf(f0.w);
  r[4]=(short)f2bf(f1.x); r[5]=(short)f2bf(f1.y); r[6]=(short)f2bf(f1.z); r[7]=(short)f2bf(f1.w);
  return r;
}

__device__ __forceinline__ void gload16(const void* g, void* l){
  __builtin_amdgcn_global_load_lds((const __attribute__((address_space(1))) unsigned int*)g,
                                   (__attribute__((address_space(3))) unsigned int*)l, 16, 0, 0);
}

// ---------------------------------------------------------------------------
// x fp32 -> bf16 cache
// ---------------------------------------------------------------------------
__global__ __launch_bounds__(256)
void xcvt_kernel(const float* __restrict__ x, unsigned short* __restrict__ xbf){
  int i = blockIdx.x * 256 + threadIdx.x;
  const float4 f0 = ((const float4*)x)[(size_t)i * 2];
  const float4 f1 = ((const float4*)x)[(size_t)i * 2 + 1];
  ushort4 o0, o1;
  o0.x = f2bf(f0.x); o0.y = f2bf(f0.y); o0.z = f2bf(f0.z); o0.w = f2bf(f0.w);
  o1.x = f2bf(f1.x); o1.y = f2bf(f1.y); o1.z = f2bf(f1.z); o1.w = f2bf(f1.w);
  ((ushort4*)xbf)[(size_t)i * 2]     = o0;
  ((ushort4*)xbf)[(size_t)i * 2 + 1] = o1;
}

// ---------------------------------------------------------------------------
// Transpose + fp32->bf16 convert:  in [E][R][C] f32  ->  out [E][C][R] bf16
// ---------------------------------------------------------------------------
__global__ __launch_bounds__(256, 4)
void transpose_cvt_kernel(const float* __restrict__ in, unsigned short* __restrict__ out,
                          int R, int C){
  const int tilesR = R >> 6, tilesC = C >> 6;
  const int b = blockIdx.x;
  const int e = b / (tilesR * tilesC);
  const int rem = b % (tilesR * tilesC);
  const int rb = (rem / tilesC) << 6;
  const int cb = (rem % tilesC) << 6;
  const float* src = in + (size_t)e * R * C;
  unsigned short* dst = out + (size_t)e * R * C;
  __shared__ float t[64][65];
  const int r0 = threadIdx.x >> 4;
  const int c4 = (threadIdx.x & 15) << 2;
  #pragma unroll
  for (int p = 0; p < 4; ++p){
    int r = r0 + (p << 4);
    const float4 v = *(const float4*)(src + (size_t)(rb + r) * C + cb + c4);
    t[r][c4+0] = v.x; t[r][c4+1] = v.y; t[r][c4+2] = v.z; t[r][c4+3] = v.w;
  }
  __syncthreads();
  #pragma unroll
  for (int p = 0; p < 4; ++p){
    int cr = r0 + (p << 4);
    ushort4 o;
    o.x = f2bf(t[c4+0][cr]); o.y = f2bf(t[c4+1][cr]);
    o.z = f2bf(t[c4+2][cr]); o.w = f2bf(t[c4+3][cr]);
    *(ushort4*)(dst + (size_t)(cb + cr) * R + rb + c4) = o;
  }
}

// ---------------------------------------------------------------------------
// Gate GEMM1 (fp32, spill-proof): h = relu(x @ gw1 + gb1) -> ghuf
// ---------------------------------------------------------------------------
__global__ __launch_bounds__(512, 4)
void gate_gemm1_kernel(const float* __restrict__ x, const float* __restrict__ gw1,
                       const float* __restrict__ gb1, float* __restrict__ h){
  __shared__ float xs[32][68];
  __shared__ float g1s[32][256];
  const int tid = threadIdx.x;
  const int t0 = blockIdx.x << 6;
  const int tg = tid >> 6;
  const int cg = tid & 63;

  const int xtok = tid >> 3, xk4 = (tid & 7) << 2;
  const int gr = tid >> 6, gc = (tid & 63) << 2;

  float acc0[4] = {0.f,0.f,0.f,0.f}, acc1[4] = {0.f,0.f,0.f,0.f};
  float acc2[4] = {0.f,0.f,0.f,0.f}, acc3[4] = {0.f,0.f,0.f,0.f};
  float acc4[4] = {0.f,0.f,0.f,0.f}, acc5[4] = {0.f,0.f,0.f,0.f};
  float acc6[4] = {0.f,0.f,0.f,0.f}, acc7[4] = {0.f,0.f,0.f,0.f};

  for (int kb = 0; kb < 512; kb += 32){
    __syncthreads();
    {
      const float4 v = *(const float4*)(x + (size_t)(t0 + xtok) * 512 + kb + xk4);
      xs[xk4+0][xtok] = v.x; xs[xk4+1][xtok] = v.y;
      xs[xk4+2][xtok] = v.z; xs[xk4+3][xtok] = v.w;
    }
    #pragma unroll
    for (int p = 0; p < 4; ++p)
      *(float4*)&g1s[(p << 3) + gr][gc] =
        *(const float4*)(gw1 + (size_t)(kb + (p << 3) + gr) * 256 + gc);
    __syncthreads();
    #pragma unroll 4
    for (int k = 0; k < 32; ++k){
      const float4 wv = *(const float4*)&g1s[k][cg << 2];
      const float4 xa = *(const float4*)&xs[k][tg << 3];
      const float4 xb = *(const float4*)&xs[k][(tg << 3) + 4];
      acc0[0]=fmaf(xa.x,wv.x,acc0[0]); acc0[1]=fmaf(xa.x,wv.y,acc0[1]);
      acc0[2]=fmaf(xa.x,wv.z,acc0[2]); acc0[3]=fmaf(xa.x,wv.w,acc0[3]);
      acc1[0]=fmaf(xa.y,wv.x,acc1[0]); acc1[1]=fmaf(xa.y,wv.y,acc1[1]);
      acc1[2]=fmaf(xa.y,wv.z,acc1[2]); acc1[3]=fmaf(xa.y,wv.w,acc1[3]);
      acc2[0]=fmaf(xa.z,wv.x,acc2[0]); acc2[1]=fmaf(xa.z,wv.y,acc2[1]);
      acc2[2]=fmaf(xa.z,wv.z,acc2[2]); acc2[3]=fmaf(xa.z,wv.w,acc2[3]);
      acc3[0]=fmaf(xa.w,wv.x,acc3[0]); acc3[1]=fmaf(xa.w,wv.y,acc3[1]);
      acc3[2]=fmaf(xa.w,wv.z,acc3[2]); acc3[3]=fmaf(xa.w,wv.w,acc3[3]);
      acc4[0]=fmaf(xb.x,wv.x,acc4[0]); acc4[1]=fmaf(xb.x,wv.y,acc4[1]);
      acc4[2]=fmaf(xb.x,wv.z,acc4[2]); acc4[3]=fmaf(xb.x,wv.w,acc4[3]);
      acc5[0]=fmaf(xb.y,wv.x,acc5[0]); acc5[1]=fmaf(xb.y,wv.y,acc5[1]);
      acc5[2]=fmaf(xb.y,wv.z,acc5[2]); acc5[3]=fmaf(xb.y,wv.w,acc5[3]);
      acc6[0]=fmaf(xb.z,wv.x,acc6[0]); acc6[1]=fmaf(xb.z,wv.y,acc6[1]);
      acc6[2]=fmaf(xb.z,wv.z,acc6[2]); acc6[3]=fmaf(xb.z,wv.w,acc6[3]);
      acc7[0]=fmaf(xb.w,wv.x,acc7[0]); acc7[1]=fmaf(xb.w,wv.y,acc7[1]);
      acc7[2]=fmaf(xb.w,wv.z,acc7[2]); acc7[3]=fmaf(xb.w,wv.w,acc7[3]);
    }
  }

  const float4 bias = *(const float4*)(gb1 + (cg << 2));
  float* hp = h + (size_t)(t0 + (tg << 3)) * 256 + (cg << 2);
  float4 o;
  #define HOUT(ACC, T) \
    o.x = fmaxf(ACC[0] + bias.x, 0.f); o.y = fmaxf(ACC[1] + bias.y, 0.f); \
    o.z = fmaxf(ACC[2] + bias.z, 0.f); o.w = fmaxf(ACC[3] + bias.w, 0.f); \
    *(float4*)(hp + (size_t)(T) * 256) = o;
  HOUT(acc0, 0) HOUT(acc1, 1) HOUT(acc2, 2) HOUT(acc3, 3)
  HOUT(acc4, 4) HOUT(acc5, 5) HOUT(acc6, 6) HOUT(acc7, 7)
  #undef HOUT
}

// ---------------------------------------------------------------------------
// Gate2: logits, softmax, top2, re-softmax, block-aggregated scatter.
// ---------------------------------------------------------------------------
__global__ __launch_bounds__(256, 2)
void gate2_kernel(const float* __restrict__ h, const float* __restrict__ gw2,
                  const float* __restrict__ gb2,
                  int* __restrict__ counts, int* __restrict__ pair_tok,
                  float* __restrict__ pair_w){
  __shared__ float g2s[256 * 9];
  __shared__ int   lcnt[8];
  __shared__ int   lbase[8];
  __shared__ int   lpre[9];
  __shared__ int   ltok[8][256];
  __shared__ float lw[8][256];
  const int tid = threadIdx.x;
  const int t0 = blockIdx.x << 8;

  #pragma unroll
  for (int p = 0; p < 8; ++p){
    int idx = tid + (p << 8);
    g2s[(idx >> 3) * 9 + (idx & 7)] = gw2[idx];
  }
  if (tid < 8) lcnt[tid] = 0;
  __syncthreads();

  const int token = t0 + tid;
  float pl[8];
  #pragma unroll
  for (int e = 0; e < 8; ++e) pl[e] = gb2[e];
  for (int j = 0; j < 64; ++j){
    const float4 hv = *(const float4*)(h + (size_t)token * 256 + (j << 2));
    #pragma unroll
    for (int i = 0; i < 4; ++i){
      const float hx = ((const float*)&hv)[i];
      #pragma unroll
      for (int e = 0; e < 8; ++e)
        pl[e] = fmaf(hx, g2s[((j << 2) + i) * 9 + e], pl[e]);
    }
  }
  float m = pl[0];
  #pragma unroll
  for (int e = 1; e < 8; ++e) m = fmaxf(m, pl[e]);
  float p[8]; float s = 0.f;
  #pragma unroll
  for (int e = 0; e < 8; ++e){ p[e] = expf(pl[e] - m); s += p[e]; }
  float inv = 1.f / s;
  float m1 = -1.f, m2 = -1.f; int i1 = 0, i2 = 0;
  #pragma unroll
  for (int e = 0; e < 8; ++e){
    float pe = p[e] * inv;
    if (pe > m1){ m2 = m1; i2 = i1; m1 = pe; i1 = e; }
    else if (pe > m2){ m2 = pe; i2 = e; }
  }
  float e21 = expf(m2 - m1);
  float w1 = 1.f / (1.f + e21);
  float w2 = 1.f - w1;
  int p1 = atomicAdd(&lcnt[i1], 1); ltok[i1][p1] = token; lw[i1][p1] = w1;
  int p2 = atomicAdd(&lcnt[i2], 1); ltok[i2][p2] = token; lw[i2][p2] = w2;
  __syncthreads();
  if (tid < 8) lbase[tid] = atomicAdd(&counts[tid], lcnt[tid]);
  if (tid == 0){
    lpre[0] = 0;
    #pragma unroll
    for (int e = 0; e < 8; ++e) lpre[e+1] = lpre[e] + lcnt[e];
  }
  __syncthreads();
  const int total = lpre[8];
  for (int idx = tid; idx < total; idx += 256){
    int e = 0;
    #pragma unroll
    for (int q = 0; q < 7; ++q) e += (idx >= lpre[q + 1]) ? 1 : 0;
    const int i = idx - lpre[e];
    const int dst = (e << 16) + lbase[e] + i;
    pair_tok[dst] = ltok[e][i];
    pair_w[dst]   = lw[e][i];
  }
}

// ---------------------------------------------------------------------------
// Scan: chunk offsets (128-token chunks) + exact token prefix offsets.
// ---------------------------------------------------------------------------
__global__ void scan_kernel(const int* __restrict__ counts, int* __restrict__ offs,
                            int* __restrict__ toffs){
  if (threadIdx.x == 0){
    int o = 0, t = 0;
    #pragma unroll
    for (int e = 0; e < 8; ++e){
      offs[e] = o; o += (counts[e] + 127) >> 7;
      toffs[e] = t; t += counts[e];
    }
    offs[8] = o; toffs[8] = t;
  }
}

// ---------------------------------------------------------------------------
// eg1: h[seq][1024] = gelu(gather(x) @ we1 + be1), bf16.
// Grid 8256 (pad of 1031 chunks x 8 ntiles), XCD-chunked swizzle: XCD owns a
// contiguous chunk range (all 8 ntiles of a chunk + neighbor chunks on one
// L2). Swapped MFMA operands: D rows = hcols (regs), D cols = tokens (lanes)
// -> h stored as ushort4 (8B).
// ---------------------------------------------------------------------------
__global__ __launch_bounds__(256, 4)
void eg1_kernel(const unsigned short* __restrict__ xbf,
                const unsigned short* __restrict__ we1T,   // [E][1024][512]
                const float* __restrict__ be1,
                const int* __restrict__ counts, const int* __restrict__ offs,
                const int* __restrict__ toffs, const int* __restrict__ pair_tok,
                unsigned short* __restrict__ h){
  // XCD-chunked remap: consecutive hw blocks round-robin XCDs; give each XCD
  // a contiguous logical range. 8256/8 = 1032 logical slots per XCD.
  const int g = (blockIdx.x & 7) * 1032 + (blockIdx.x >> 3);
  const int chunk = g >> 3, nt = g & 7;
  if (chunk >= offs[8]) return;
  int e = 0;
  #pragma unroll
  for (int q = 0; q < 7; ++q) e += (chunk >= offs[q+1]) ? 1 : 0;
  const int cnt = counts[e];
  const int base = (chunk - offs[e]) << 7;
  const int n0 = nt << 7;
  const int tid = threadIdx.x;
  const int lane = tid & 63;
  const int wv = tid >> 6;
  const int wr = wv >> 1, wc = wv & 1;
  const int lrow = lane & 15, kgrp = lane >> 4;

  __shared__ char lds[32768];
  char* const As = lds;
  char* const Bs = lds + 16384;

  const int srow = tid >> 3;
  const int sdelta = ((tid & 7) << 4) ^ ((srow & 7) << 4);
  unsigned aoff[4];
  #pragma unroll
  for (int i = 0; i < 4; ++i){
    int rr = base + srow + (i << 5);
    int tok = (rr < cnt) ? pair_tok[(e << 16) + rr] : 0;
    aoff[i] = ((unsigned)tok) << 10;      // tok * 512 elems * 2B
  }
  const char* const xb  = (const char*)xbf;
  const char* const w1b = (const char*)we1T + ((size_t)e << 20);

  f32x4 acc[4][4];                         // [hcol-frag][token-frag]
  #pragma unroll
  for (int i = 0; i < 4; ++i)
    #pragma unroll
    for (int j = 0; j < 4; ++j) acc[i][j] = (f32x4)0.f;

  const int sw = (lrow & 7) << 4;
  for (int kb = 0; kb < 8; ++kb){
    #pragma unroll
    for (int i = 0; i < 4; ++i)
      gload16(xb + aoff[i] + (kb << 7) + sdelta, As + (tid << 4) + (i << 12));
    #pragma unroll
    for (int i = 0; i < 4; ++i)
      gload16(w1b + (size_t)(n0 + srow + (i << 5)) * 1024 + (kb << 7) + sdelta,
              Bs + (tid << 4) + (i << 12));
    __syncthreads();
    #pragma unroll
    for (int s = 0; s < 2; ++s){
      const int kbyte = ((s << 6) + (kgrp << 4)) ^ sw;
      bf16x8 af[4], bf[4];
      #pragma unroll
      for (int f = 0; f < 4; ++f){
        af[f] = *(const bf16x8*)(As + ((wr << 6) + (f << 4) + lrow) * 128 + kbyte);
        bf[f] = *(const bf16x8*)(Bs + ((wc << 6) + (f << 4) + lrow) * 128 + kbyte);
      }
      #pragma unroll
      for (int fb = 0; fb < 4; ++fb)
        #pragma unroll
        for (int fa = 0; fa < 4; ++fa)
          acc[fb][fa] = __builtin_amdgcn_mfma_f32_16x16x32_bf16(bf[fb], af[fa], acc[fb][fa], 0, 0, 0);
    }
    __syncthreads();
  }

  // epilogue: D[row=hcol][col=token]; 8B ushort4 stores.
  const int hrow0 = toffs[e] + base;
  float4 bias4[4];
  #pragma unroll
  for (int fb = 0; fb < 4; ++fb)
    bias4[fb] = *(const float4*)(be1 + (e << 10) + n0 + (wc << 6) + (fb << 4) + (kgrp << 2));
  #pragma unroll
  for (int fa = 0; fa < 4; ++fa){
    const int tl = (wr << 6) + (fa << 4) + lrow;       // local token row
    if (base + tl < cnt){
      unsigned short* hp = h + (size_t)(hrow0 + tl) * 1024 + n0 + (wc << 6) + (kgrp << 2);
      #pragma unroll
      for (int fb = 0; fb < 4; ++fb){
        float v, gl; ushort4 o;
        v = acc[fb][fa][0] + bias4[fb].x; gl = 0.5f*v*(1.f+erff(v*0.70710678118654752f)); o.x = f2bf(gl);
        v = acc[fb][fa][1] + bias4[fb].y; gl = 0.5f*v*(1.f+erff(v*0.70710678118654752f)); o.y = f2bf(gl);
        v = acc[fb][fa][2] + bias4[fb].z; gl = 0.5f*v*(1.f+erff(v*0.70710678118654752f)); o.z = f2bf(gl);
        v = acc[fb][fa][3] + bias4[fb].w; gl = 0.5f*v*(1.f+erff(v*0.70710678118654752f)); o.w = f2bf(gl);
        *(ushort4*)(hp + (fb << 4)) = o;
      }
    }
  }
}

// ---------------------------------------------------------------------------
// eg2: out[tok] += w * (h @ we2 + be2). A = h rows (seq-linear). Grid 4128,
// same XCD-chunked swizzle (4128/8 = 516 slots -> 129 chunks per XCD).
// ---------------------------------------------------------------------------
__global__ __launch_bounds__(256, 4)
void eg2_kernel(const unsigned short* __restrict__ h,
                const unsigned short* __restrict__ we2T,   // [E][512][1024]
                const float* __restrict__ be2,
                const int* __restrict__ counts, const int* __restrict__ offs,
                const int* __restrict__ toffs, const int* __restrict__ pair_tok,
                const float* __restrict__ pair_w,
                float* __restrict__ out){
  const int g = (blockIdx.x & 7) * 516 + (blockIdx.x >> 3);
  const int chunk = g >> 2, nt = g & 3;
  if (chunk >= offs[8]) return;
  int e = 0;
  #pragma unroll
  for (int q = 0; q < 7; ++q) e += (chunk >= offs[q+1]) ? 1 : 0;
  const int cnt = counts[e];
  const int base = (chunk - offs[e]) << 7;
  const int n0 = nt << 7;
  const int tid = threadIdx.x;
  const int lane = tid & 63;
  const int wv = tid >> 6;
  const int wr = wv >> 1, wc = wv & 1;
  const int lrow = lane & 15, kgrp = lane >> 4;

  __shared__ char lds[32768];
  char* const As = lds;
  char* const Bs = lds + 16384;

  const int srow = tid >> 3;
  const int sdelta = ((tid & 7) << 4) ^ ((srow & 7) << 4);
  const char* const hb  = (const char*)h + (size_t)(toffs[e] + base) * 2048;
  const char* const w2b = (const char*)we2T + ((size_t)e << 20);

  f32x4 acc[4][4];
  #pragma unroll
  for (int i = 0; i < 4; ++i)
    #pragma unroll
    for (int j = 0; j < 4; ++j) acc[i][j] = (f32x4)0.f;

  const int sw = (lrow & 7) << 4;
  for (int kb = 0; kb < 16; ++kb){
    #pragma unroll
    for (int i = 0; i < 4; ++i)
      gload16(hb + (size_t)(srow + (i << 5)) * 2048 + (kb << 7) + sdelta,
              As + (tid << 4) + (i << 12));
    #pragma unroll
    for (int i = 0; i < 4; ++i)
      gload16(w2b + (size_t)(n0 + srow + (i << 5)) * 2048 + (kb << 7) + sdelta,
              Bs + (tid << 4) + (i << 12));
    __syncthreads();
    #pragma unroll
    for (int s = 0; s < 2; ++s){
      const int kbyte = ((s << 6) + (kgrp << 4)) ^ sw;
      bf16x8 af[4], bf[4];
      #pragma unroll
      for (int f = 0; f < 4; ++f){
        af[f] = *(const bf16x8*)(As + ((wr << 6) + (f << 4) + lrow) * 128 + kbyte);
        bf[f] = *(const bf16x8*)(Bs + ((wc << 6) + (f << 4) + lrow) * 128 + kbyte);
      }
      #pragma unroll
      for (int fr = 0; fr < 4; ++fr)
        #pragma unroll
        for (int fc = 0; fc < 4; ++fc)
          acc[fr][fc] = __builtin_amdgcn_mfma_f32_16x16x32_bf16(af[fr], bf[fc], acc[fr][fc], 0, 0, 0);
    }
    __syncthreads();
  }

  float bias2[4];
  #pragma unroll
  for (int fc = 0; fc < 4; ++fc)
    bias2[fc] = be2[(e << 9) + n0 + (wc << 6) + (fc << 4) + lrow];

  #pragma unroll
  for (int fr = 0; fr < 4; ++fr){
    #pragma unroll
    for (int rg = 0; rg < 4; ++rg){
      const int rloc = (wr << 6) + (fr << 4) + (kgrp << 2) + rg;
      const int r = base + rloc;
      if (r < cnt){
        const int tok = pair_tok[(e << 16) + r];
        const float wgt = pair_w[(e << 16) + r];
        float* const orow = out + (size_t)tok * 512 + n0 + (wc << 6) + lrow;
        #pragma unroll
        for (int fc = 0; fc < 4; ++fc)
          atomicAdd(orow + (fc << 4), wgt * (acc[fr][fc][rg] + bias2[fc]));
      }
    }
  }
}

// ---------------------------------------------------------------------------
// Fallback fused expert (R6) - used only if ws too small for h buffer.
// ---------------------------------------------------------------------------
#define VW2() asm volatile("s_waitcnt vmcnt(2)" ::: "memory")
#define BAR() __builtin_amdgcn_s_barrier()
#define SB0() __builtin_amdgcn_sched_barrier(0)

#define G1_MFMA(S, BUF) do{ \
  __builtin_amdgcn_s_setprio(1); \
  _Pragma("unroll") \
  for (int ct = 0; ct < 4; ++ct){ \
    const int col = (ct << 4) + lrow; \
    const int swc = (col & 7) << 4; \
    _Pragma("unroll") \
    for (int k2 = 0; k2 < 4; ++k2){ \
      const int byt = (col << 8) + ((((k2) << 6) + (kgrp << 4)) ^ swc); \
      bf16x8 bfr = *(const bf16x8*)((const char*)(BUF) + byt); \
      hacc[ct] = __builtin_amdgcn_mfma_f32_16x16x32_bf16(a[(S)*4 + k2], bfr, hacc[ct], 0, 0, 0); \
    } \
  } \
  __builtin_amdgcn_s_setprio(0); \
}while(0)

#define G2_MFMA(NB, BUF) do{ \
  __builtin_amdgcn_s_setprio(1); \
  _Pragma("unroll") \
  for (int nt2 = 0; nt2 < 8; ++nt2){ \
    const int col = (nt2 << 4) + lrow; \
    const int swc = (col & 7) << 4; \
    _Pragma("unroll") \
    for (int k2 = 0; k2 < 2; ++k2){ \
      const int byt = (col << 7) + (((k2 << 6) + (kgrp << 4)) ^ swc); \
      bf16x8 bfr = *(const bf16x8*)((const char*)(BUF) + byt); \
      acc[(NB)*8 + nt2] = __builtin_amdgcn_mfma_f32_16x16x32_bf16(a2[k2], bfr, acc[(NB)*8 + nt2], 0, 0, 0); \
    } \
  } \
  __builtin_amdgcn_s_setprio(0); \
}while(0)

#define PHASE(STAGE_STMT, MFMA_STMT) do{ \
  STAGE_STMT; VW2(); BAR(); SB0(); MFMA_STMT; SB0(); BAR(); }while(0)

__global__ __launch_bounds__(512, 2)
void expert_kernel(const unsigned short* __restrict__ xbf,
                   const unsigned short* __restrict__ we1T,
                   const unsigned short* __restrict__ we2T,
                   const float* __restrict__ be1, const float* __restrict__ be2,
                   const int* __restrict__ counts, const int* __restrict__ offs,
                   const int* __restrict__ pair_tok, const float* __restrict__ pair_w,
                   float* __restrict__ out){
  const int b = blockIdx.x;
  if (b >= offs[8]) return;
  int e = 0;
  #pragma unroll
  for (int q = 0; q < 7; ++q) e += (b >= offs[q + 1]) ? 1 : 0;
  const int cnt = counts[e];
  const int base = (b - offs[e]) << 7;
  const int tid = threadIdx.x;
  const int wv = tid >> 6;
  const int lane = tid & 63;
  const int lrow = lane & 15;
  const int kgrp = lane >> 4;

  __shared__ unsigned short w1s0[64 * 128];
  __shared__ unsigned short w1s1[64 * 128];
  __shared__ unsigned short w2s0[128 * 64];
  __shared__ unsigned short w2s1[128 * 64];
  __shared__ unsigned short hs[128 * 64];

  bf16x8 a[16];
  {
    int r = base + (wv << 4) + lrow;
    int tok = (r < cnt) ? pair_tok[(e << 16) + r] : 0;
    const unsigned short* xr = xbf + (size_t)tok * 512 + (kgrp << 3);
    #pragma unroll
    for (int kc = 0; kc < 16; ++kc)
      a[kc] = *(const bf16x8*)(xr + (kc << 5));
  }
  f32x4 acc[32];
  #pragma unroll
  for (int i = 0; i < 32; ++i) acc[i] = (f32x4)0.f;

  const unsigned short* w1g = we1T + ((size_t)e << 19);
  const unsigned short* w2g = we2T + ((size_t)e << 19);

  auto stage_w1 = [&](int hcv, int s, unsigned short* buf){
    #pragma unroll
    for (int i = 0; i < 2; ++i){
      int bb = (((wv << 1) + i) << 10) + (lane << 4);
      int row = bb >> 8;
      int inner = bb & 255;
      int srcb = ((hcv + row) << 10) + (s << 8) + (inner ^ ((row & 7) << 4));
      gload16((const char*)w1g + srcb, (char*)buf + (((wv << 1) + i) << 10));
    }
  };
  auto stage_w2 = [&](int hcv, int nb, unsigned short* buf){
    #pragma unroll
    for (int i = 0; i < 2; ++i){
      int bb = (((wv << 1) + i) << 10) + (lane << 4);
      int row = bb >> 7;
      int inner = bb & 127;
      int srcb = (((nb << 7) + row) << 11) + (hcv << 1) + (inner ^ ((row & 7) << 4));
      gload16((const char*)w2g + srcb, (char*)buf + (((wv << 1) + i) << 10));
    }
  };

  stage_w1(0, 0, w1s0);

  for (int hc = 0; hc < 1024; hc += 64){
    f32x4 hacc[4];
    #pragma unroll
    for (int i = 0; i < 4; ++i) hacc[i] = (f32x4)0.f;

    PHASE(stage_w1(hc, 1, w1s1), G1_MFMA(0, w1s0));
    PHASE(stage_w1(hc, 2, w1s0), G1_MFMA(1, w1s1));
    PHASE(stage_w1(hc, 3, w1s1), G1_MFMA(2, w1s0));
    PHASE(stage_w2(hc, 0, w2s0), G1_MFMA(3, w1s1));

    bf16x8 a2[2];
    {
      char* const hsb = (char*)hs;
      #pragma unroll
      for (int ct = 0; ct < 4; ++ct){
        int colL = (ct << 4) + lrow;
        float bias = be1[(e << 10) + hc + colL];
        #pragma unroll
        for (int rr = 0; rr < 4; ++rr){
          int rowL = (wv << 4) + (kgrp << 2) + rr;
          float v = hacc[ct][rr] + bias;
          float g = 0.5f * v * (1.f + erff(v * 0.70710678118654752f));
          int byt = (rowL << 7) + (colL << 1);
          *(unsigned short*)(hsb + (byt ^ ((rowL & 7) << 4))) = f2bf(g);
        }
      }
      const char* const hsc = (const char*)hs;
      int rowL = (wv << 4) + lrow;
      int swr = (rowL & 7) << 4;
      #pragma unroll
      for (int k2 = 0; k2 < 2; ++k2){
        int byt = (rowL << 7) + (((k2 << 6) + (kgrp << 4)) ^ swr);
        a2[k2] = *(const bf16x8*)(hsc + byt);
      }
    }

    PHASE(stage_w2(hc, 1, w2s1),               G2_MFMA(0, w2s0));
    PHASE(stage_w2(hc, 2, w2s0),               G2_MFMA(1, w2s1));
    PHASE(stage_w2(hc, 3, w2s1),               G2_MFMA(2, w2s0));
    PHASE(stage_w1((hc + 64) & 1023, 0, w1s0), G2_MFMA(3, w2s1));
  }

  #pragma unroll
  for (int rr = 0; rr < 4; ++rr){
    int rowL = (wv << 4) + (kgrp << 2) + rr;
    int rg = base + rowL;
    if (rg < cnt){
      int tok = pair_tok[(e << 16) + rg];
      float wp = pair_w[(e << 16) + rg];
      float* orow = out + (size_t)tok * 512;
      #pragma unroll
      for (int tl = 0; tl < 32; ++tl){
        int col = (tl << 4) + lrow;
        atomicAdd(orow + col, wp * (acc[tl][rr] + be2[(e << 9) + col]));
      }
    }
  }
}

// ---------------------------------------------------------------------------
extern "C" void kernel_launch(void* const* d_in, const int* in_sizes, int n_in,
                              void* d_out, int out_size, void* d_ws, size_t ws_size,
                              hipStream_t stream){
  const float* x   = (const float*)d_in[0];
  const float* gw1 = (const float*)d_in[1];
  const float* gb1 = (const float*)d_in[2];
  const float* gw2 = (const float*)d_in[3];
  const float* gb2 = (const float*)d_in[4];
  const float* we1 = (const float*)d_in[5];
  const float* be1 = (const float*)d_in[6];
  const float* we2 = (const float*)d_in[7];
  const float* be2 = (const float*)d_in[8];
  float* out = (float*)d_out;

  char* ws = (char*)d_ws;
  const size_t MiB = 1024 * 1024;
  unsigned short* we1T = (unsigned short*)(ws);                 // 8 MiB
  unsigned short* we2T = (unsigned short*)(ws + 8 * MiB);       // 8 MiB
  int*   pair_tok = (int*)  (ws + 16 * MiB);                    // 2 MiB
  float* pair_w   = (float*)(ws + 18 * MiB);                    // 2 MiB
  int*   counts   = (int*)  (ws + 20 * MiB);                    // 64 B
  int*   offs     = (int*)  (ws + 20 * MiB + 256);              // 64 B
  int*   toffs    = (int*)  (ws + 20 * MiB + 512);              // 64 B
  unsigned short* xbf  = (unsigned short*)(ws + 21 * MiB);      // 64 MiB
  float* ghuf          = (float*)(ws + 85 * MiB);               // 64 MiB (gate h)
  unsigned short* hexp = (unsigned short*)(ws + 85 * MiB);      // 257 MiB, aliases
                                                                // ghuf (stream-ordered)
  const bool big = ws_size >= 344 * MiB;

  hipMemsetAsync(d_out, 0, (size_t)out_size * sizeof(float), stream);
  hipMemsetAsync(counts, 0, 256, stream);

  hipLaunchKernelGGL(xcvt_kernel, dim3(16384), dim3(256), 0, stream, x, xbf);
  hipLaunchKernelGGL(transpose_cvt_kernel, dim3(1024), dim3(256), 0, stream,
                     we1, we1T, 512, 1024);
  hipLaunchKernelGGL(transpose_cvt_kernel, dim3(1024), dim3(256), 0, stream,
                     we2, we2T, 1024, 512);
  hipLaunchKernelGGL(gate_gemm1_kernel, dim3(1024), dim3(512), 0, stream,
                     x, gw1, gb1, ghuf);
  hipLaunchKernelGGL(gate2_kernel, dim3(256), dim3(256), 0, stream,
                     ghuf, gw2, gb2, counts, pair_tok, pair_w);
  hipLaunchKernelGGL(scan_kernel, dim3(1), dim3(64), 0, stream, counts, offs, toffs);

  if (big){
    hipLaunchKernelGGL(eg1_kernel, dim3(8256), dim3(256), 0, stream,
                       xbf, we1T, be1, counts, offs, toffs, pair_tok, hexp);
    hipLaunchKernelGGL(eg2_kernel, dim3(4128), dim3(256), 0, stream,
                       hexp, we2T, be2, counts, offs, toffs, pair_tok, pair_w, out);
  } else {
    hipLaunchKernelGGL(expert_kernel, dim3(1032), dim3(512), 0, stream,
                       xbf, we1T, we2T, be1, be2, counts, offs, pair_tok, pair_w, out);
  }
}